// Round 16
// baseline (4536.770 us; speedup 1.0000x reference)
//
#include <hip/hip_runtime.h>
#include <hip/hip_bf16.h>
#include <math.h>
#include <float.h>

#define NUM_CB 8
#define CB_SIZE 256
#define DIM 128
#define BT (16 * 16384)                  // 262144 tokens
#define Q_ELEMS ((size_t)BT * DIM)       // 33554432
#define I_ELEMS ((size_t)BT * NUM_CB)    // 2097152

#define TC 64                            // candidates per streamed tile
#define TILES_PER_CB (CB_SIZE / TC)      // 4
#define TILE_BYTES 32768                 // 2 planes x 64 cand x 16 slots x 16B

// Pass-A ambiguity margin (validated rounds 6-15). Do not shrink.
#define MARGIN_A 1.5e-4f

typedef short  bf16x8 __attribute__((ext_vector_type(8)));
typedef float  f32x4  __attribute__((ext_vector_type(4)));

__device__ __forceinline__ unsigned short bf16_rne(float f) {
    unsigned int u = __float_as_uint(f);
    u = u + 0x7FFFu + ((u >> 16) & 1u);
    return (unsigned short)(u >> 16);
}
__device__ __forceinline__ float bf16_tof(unsigned short h) {
    return __uint_as_float(((unsigned int)h) << 16);
}
__device__ __forceinline__ unsigned short f2bf(float f) {
    __hip_bfloat16 h = __float2bfloat16(f);
    return *reinterpret_cast<unsigned short*>(&h);
}

// ---------------------------------------------------------------------------
// VALIDATED np emulation (rounds 6-15): pairwise-8 sum-of-squares, no FMA.
// ---------------------------------------------------------------------------
__device__ __forceinline__ float np_sum_sq_128(const float* a) {
#pragma clang fp contract(off)
    float r0 = 0.f, r1 = 0.f, r2 = 0.f, r3 = 0.f,
          r4 = 0.f, r5 = 0.f, r6 = 0.f, r7 = 0.f;
#pragma unroll
    for (int i = 0; i < DIM; i += 8) {
        r0 = r0 + a[i + 0] * a[i + 0];
        r1 = r1 + a[i + 1] * a[i + 1];
        r2 = r2 + a[i + 2] * a[i + 2];
        r3 = r3 + a[i + 3] * a[i + 3];
        r4 = r4 + a[i + 4] * a[i + 4];
        r5 = r5 + a[i + 5] * a[i + 5];
        r6 = r6 + a[i + 6] * a[i + 6];
        r7 = r7 + a[i + 7] * a[i + 7];
    }
    return ((r0 + r1) + (r2 + r3)) + ((r4 + r5) + (r6 + r7));
}

__global__ void rvq_esq_kernel(const float* __restrict__ cb,
                               float* __restrict__ esq) {
    int i = blockIdx.x * blockDim.x + threadIdx.x;   // 0 .. 2047
    if (i >= NUM_CB * CB_SIZE) return;
    esq[i] = np_sum_sq_128(cb + (size_t)i * DIM);
}

// Transposed f32 codebook for coalesced Pass-B reads: cbT[k][d][c]
__global__ void rvq_transpose_kernel(const float* __restrict__ cb,
                                     float* __restrict__ cbT) {
    int idx = blockIdx.x * blockDim.x + threadIdx.x;   // 0 .. 262143
    if (idx >= NUM_CB * DIM * CB_SIZE) return;
    int c = idx & (CB_SIZE - 1);
    int d = (idx >> 8) & (DIM - 1);
    int k = idx >> 15;
    cbT[idx] = cb[((size_t)(k * CB_SIZE + c)) * DIM + d];
}

// ---------------------------------------------------------------------------
// Precompute merged bf16 hi|lo image in the swizzled LDS layout (validated):
// img[t*2048 + plane*1024 + cand*16 + (slot ^ (cand&15))], t = k*4 + T,
// codeword = t*64 + cand.
// ---------------------------------------------------------------------------
__global__ void rvq_split_kernel(const float* __restrict__ cb,
                                 bf16x8* __restrict__ g_img) {
    int idx = blockIdx.x * blockDim.x + threadIdx.x;   // 0 .. 32767
    if (idx >= NUM_CB * CB_SIZE * 16) return;
    int slot = idx & 15;
    int cand = (idx >> 4) & (TC - 1);
    int t    = idx >> 10;                 // 0..31
    const float* src = cb + ((size_t)t * TC + cand) * DIM + slot * 8;
    float4 a = *reinterpret_cast<const float4*>(src);
    float4 b = *reinterpret_cast<const float4*>(src + 4);
    float e[8] = {a.x, a.y, a.z, a.w, b.x, b.y, b.z, b.w};
    bf16x8 eh, el;
#pragma unroll
    for (int i = 0; i < 8; ++i) {
        unsigned short h = bf16_rne(e[i]);
        float rem = e[i] - bf16_tof(h);
        eh[i] = (short)h;
        el[i] = (short)bf16_rne(rem);
    }
    int ds = slot ^ (cand & 15);
    g_img[(size_t)t * 2048 + cand * 16 + ds]        = eh;
    g_img[(size_t)t * 2048 + 1024 + cand * 16 + ds] = el;
}

// DMA one 32KB tile into LDS buffer: 8 x global_load_lds(16B) per wave (4 wv).
__device__ __forceinline__ void stage_tile(const bf16x8* __restrict__ g_img,
                                           bf16x8 (*s_buf)[2048],
                                           int t, int nb, int wid, int lane) {
    const char* gt = (const char*)g_img + (size_t)t * TILE_BYTES
                     + wid * 8192 + lane * 16;
    const char* lb = (const char*)(&s_buf[nb][0]) + wid * 8192;  // wave-uniform
#pragma unroll
    for (int c = 0; c < 8; ++c) {
        __builtin_amdgcn_global_load_lds(
            (const __attribute__((address_space(1))) unsigned int*)(gt + c * 1024),
            (__attribute__((address_space(3))) unsigned int*)(lb + c * 1024),
            16, 0, 0);
    }
}

// ---------------------------------------------------------------------------
// Main fused kernel: 128 tokens/block (4 waves x 32), residual in VGPRs.
// SWAPPED MFMA + DUAL TOKEN GROUPS: each codebook A-frag (bh/bl) read from
// LDS once feeds MFMAs for TWO 16-token residual groups -> ds_read/token
// halved. __launch_bounds__(256) with NO occupancy arg: the allocator is
// free to use ~200 VGPRs (m97 precedent: 164 with plain (256)). 512-thread
// blocks pin the cap at 128 and spill (r13/r15 evidence).
// ---------------------------------------------------------------------------
__global__ __launch_bounds__(256) void rvq_mfma_kernel(
    const float* __restrict__ z,
    const float* __restrict__ cb,
    const float* __restrict__ cbT,
    const float* __restrict__ esq,
    const bf16x8* __restrict__ g_img,
    float* __restrict__ out_q,
    float* __restrict__ out_idx,
    double* __restrict__ loss_acc) {

    __shared__ bf16x8 s_buf[2][2048];                // 2 x 32KB double buffer
    __shared__ __align__(16) float s_rbuf[4][DIM];   // per-wave passB residual
    __shared__ double s_wsum[4];

    const int tid  = threadIdx.x;
    const int wid  = tid >> 6;
    const int lane = tid & 63;
    const int lrow = lane & 15;       // token-in-group (B col / D col)
    const int lq   = lane >> 4;       // k-chunk group / D row group
    const int tokw = blockIdx.x * 128 + wid * 32;
    const int tok1 = tokw + lrow;           // group 0 token
    const int tok2 = tokw + 16 + lrow;      // group 1 token

    // ---- residual chunks: rg[s][i] = z[tok][32s + 8lq + i] ----
    float r1[4][8], r2[4][8];
    {
        const float* zp1 = z + (size_t)tok1 * DIM + 8 * lq;
        const float* zp2 = z + (size_t)tok2 * DIM + 8 * lq;
#pragma unroll
        for (int s = 0; s < 4; ++s) {
            float4 a = *reinterpret_cast<const float4*>(zp1 + 32 * s);
            float4 b = *reinterpret_cast<const float4*>(zp1 + 32 * s + 4);
            r1[s][0] = a.x; r1[s][1] = a.y; r1[s][2] = a.z; r1[s][3] = a.w;
            r1[s][4] = b.x; r1[s][5] = b.y; r1[s][6] = b.z; r1[s][7] = b.w;
            float4 c = *reinterpret_cast<const float4*>(zp2 + 32 * s);
            float4 d = *reinterpret_cast<const float4*>(zp2 + 32 * s + 4);
            r2[s][0] = c.x; r2[s][1] = c.y; r2[s][2] = c.z; r2[s][3] = c.w;
            r2[s][4] = d.x; r2[s][5] = d.y; r2[s][6] = d.z; r2[s][7] = d.w;
        }
    }

    // ---- bf16 hi/mid splits (HW RNE casts; margin-covered) ----
    bf16x8 ah1[4], am1[4], ah2[4], am2[4];
#pragma unroll
    for (int s = 0; s < 4; ++s)
#pragma unroll
        for (int i = 0; i < 8; ++i) {
            unsigned short h1 = f2bf(r1[s][i]);
            ah1[s][i] = (short)h1;
            am1[s][i] = (short)f2bf(r1[s][i] - bf16_tof(h1));
            unsigned short h2 = f2bf(r2[s][i]);
            ah2[s][i] = (short)h2;
            am2[s][i] = (short)f2bf(r2[s][i] - bf16_tof(h2));
        }

    double lsum = 0.0;

    // prologue: stage tile 0
    stage_tile(g_img, s_buf, 0, 0, wid, lane);
    asm volatile("s_waitcnt vmcnt(0)" ::: "memory");
    __syncthreads();

    for (int k = 0; k < NUM_CB; ++k) {
        const float* esqk = esq + k * CB_SIZE;
        const float* cbk  = cb  + (size_t)k * CB_SIZE * DIM;
        const float* cbTk = cbT + (size_t)k * DIM * CB_SIZE + lane;

        float g1m1 = FLT_MAX, g1m2 = FLT_MAX;
        float g2m1 = FLT_MAX, g2m2 = FLT_MAX;
        int   g1i1 = 0x7fffffff, g2i1 = 0x7fffffff;

#pragma unroll
        for (int T = 0; T < TILES_PER_CB; ++T) {
            const int t  = k * TILES_PER_CB + T;
            const int nb = T & 1;
            if (k < NUM_CB - 1 || T < TILES_PER_CB - 1)
                stage_tile(g_img, s_buf, t + 1, nb ^ 1, wid, lane);

#pragma unroll
            for (int ctl = 0; ctl < 4; ++ctl) {   // 16-candidate column tiles
                const int ctg  = T * 4 + ctl;     // global ct 0..15
                const int base = (ctl * 16 + lrow) * 16;
                bf16x8 bh[4], bl[4];
#pragma unroll
                for (int s = 0; s < 4; ++s) {
                    int ls = (4 * s + lq) ^ lrow;
                    bh[s] = s_buf[nb][base + ls];
                    bl[s] = s_buf[nb][1024 + base + ls];
                }
                // group 1
                f32x4 acc10 = {0.f, 0.f, 0.f, 0.f};
                f32x4 acc11 = {0.f, 0.f, 0.f, 0.f};
                acc10 = __builtin_amdgcn_mfma_f32_16x16x32_bf16(bh[0], ah1[0], acc10, 0, 0, 0);
                acc10 = __builtin_amdgcn_mfma_f32_16x16x32_bf16(bh[1], ah1[1], acc10, 0, 0, 0);
                acc11 = __builtin_amdgcn_mfma_f32_16x16x32_bf16(bh[2], ah1[2], acc11, 0, 0, 0);
                acc11 = __builtin_amdgcn_mfma_f32_16x16x32_bf16(bh[3], ah1[3], acc11, 0, 0, 0);
                acc10 = __builtin_amdgcn_mfma_f32_16x16x32_bf16(bh[0], am1[0], acc10, 0, 0, 0);
                acc10 = __builtin_amdgcn_mfma_f32_16x16x32_bf16(bh[1], am1[1], acc10, 0, 0, 0);
                acc11 = __builtin_amdgcn_mfma_f32_16x16x32_bf16(bh[2], am1[2], acc11, 0, 0, 0);
                acc11 = __builtin_amdgcn_mfma_f32_16x16x32_bf16(bh[3], am1[3], acc11, 0, 0, 0);
                acc10 = __builtin_amdgcn_mfma_f32_16x16x32_bf16(bl[0], ah1[0], acc10, 0, 0, 0);
                acc10 = __builtin_amdgcn_mfma_f32_16x16x32_bf16(bl[1], ah1[1], acc10, 0, 0, 0);
                acc11 = __builtin_amdgcn_mfma_f32_16x16x32_bf16(bl[2], ah1[2], acc11, 0, 0, 0);
                acc11 = __builtin_amdgcn_mfma_f32_16x16x32_bf16(bl[3], ah1[3], acc11, 0, 0, 0);
                // group 2 (reuses bh/bl -- the halved ds_read win)
                f32x4 acc20 = {0.f, 0.f, 0.f, 0.f};
                f32x4 acc21 = {0.f, 0.f, 0.f, 0.f};
                acc20 = __builtin_amdgcn_mfma_f32_16x16x32_bf16(bh[0], ah2[0], acc20, 0, 0, 0);
                acc20 = __builtin_amdgcn_mfma_f32_16x16x32_bf16(bh[1], ah2[1], acc20, 0, 0, 0);
                acc21 = __builtin_amdgcn_mfma_f32_16x16x32_bf16(bh[2], ah2[2], acc21, 0, 0, 0);
                acc21 = __builtin_amdgcn_mfma_f32_16x16x32_bf16(bh[3], ah2[3], acc21, 0, 0, 0);
                acc20 = __builtin_amdgcn_mfma_f32_16x16x32_bf16(bh[0], am2[0], acc20, 0, 0, 0);
                acc20 = __builtin_amdgcn_mfma_f32_16x16x32_bf16(bh[1], am2[1], acc20, 0, 0, 0);
                acc21 = __builtin_amdgcn_mfma_f32_16x16x32_bf16(bh[2], am2[2], acc21, 0, 0, 0);
                acc21 = __builtin_amdgcn_mfma_f32_16x16x32_bf16(bh[3], am2[3], acc21, 0, 0, 0);
                acc20 = __builtin_amdgcn_mfma_f32_16x16x32_bf16(bl[0], ah2[0], acc20, 0, 0, 0);
                acc20 = __builtin_amdgcn_mfma_f32_16x16x32_bf16(bl[1], ah2[1], acc20, 0, 0, 0);
                acc21 = __builtin_amdgcn_mfma_f32_16x16x32_bf16(bl[2], ah2[2], acc21, 0, 0, 0);
                acc21 = __builtin_amdgcn_mfma_f32_16x16x32_bf16(bl[3], ah2[3], acc21, 0, 0, 0);

                // scores: candidate c = ctg*16 + 4*lq + j for each group's token
                float4 ev = *reinterpret_cast<const float4*>(
                    esqk + ctg * 16 + 4 * lq);
                const float es[4] = {ev.x, ev.y, ev.z, ev.w};
                const int cb0 = ctg * 16 + 4 * lq;
#pragma unroll
                for (int j = 0; j < 4; ++j) {
                    float s1 = fmaf(-2.0f, acc10[j] + acc11[j], es[j]);
                    g1m2 = __builtin_amdgcn_fmed3f(g1m1, g1m2, s1);
                    if (s1 < g1m1) { g1i1 = cb0 + j; }
                    g1m1 = fminf(g1m1, s1);
                    float s2 = fmaf(-2.0f, acc20[j] + acc21[j], es[j]);
                    g2m2 = __builtin_amdgcn_fmed3f(g2m1, g2m2, s2);
                    if (s2 < g2m1) { g2i1 = cb0 + j; }
                    g2m1 = fminf(g2m1, s2);
                }
            }

            if (T == TILES_PER_CB - 1) {
                // ============== per-codebook epilogue (wave-internal) ======
                // cross-lq top-2 lexicographic reduce (2 butterfly steps)
#pragma unroll
                for (int d = 16; d < 64; d <<= 1) {
                    float o1 = __shfl_xor(g1m1, d);
                    float o2 = __shfl_xor(g1m2, d);
                    int   oi = __shfl_xor(g1i1, d);
                    bool ow = (o1 < g1m1) || (o1 == g1m1 && oi < g1i1);
                    float lo = ow ? g1m1 : o1;
                    g1m1 = ow ? o1 : g1m1;
                    g1i1 = ow ? oi : g1i1;
                    g1m2 = fminf(fminf(g1m2, o2), lo);
                    float p1 = __shfl_xor(g2m1, d);
                    float p2 = __shfl_xor(g2m2, d);
                    int   pi = __shfl_xor(g2i1, d);
                    bool pw = (p1 < g2m1) || (p1 == g2m1 && pi < g2i1);
                    float plo = pw ? g2m1 : p1;
                    g2m1 = pw ? p1 : g2m1;
                    g2i1 = pw ? pi : g2i1;
                    g2m2 = fminf(fminf(g2m2, p2), plo);
                }
                int cmin1 = g1i1, cmin2 = g2i1;

                // Pass B (rare): exact np argmin per ambiguous token (both
                // groups), coalesced cbT (validated rounds 10-15).
#pragma unroll
                for (int grp = 0; grp < 2; ++grp) {
                    bool amb = grp == 0 ? !(g1m2 - g1m1 > MARGIN_A)
                                        : !(g2m2 - g2m1 > MARGIN_A);
                    unsigned long long mask = __ballot(amb && lane < 16);
                    while (mask) {
                        int srct = __ffsll(mask) - 1;
                        mask &= mask - 1;
                        if (lrow == srct) {
#pragma unroll
                            for (int s = 0; s < 4; ++s) {
                                float4* dst = reinterpret_cast<float4*>(
                                    &s_rbuf[wid][32 * s + 8 * lq]);
                                if (grp == 0) {
                                    dst[0] = make_float4(r1[s][0], r1[s][1], r1[s][2], r1[s][3]);
                                    dst[1] = make_float4(r1[s][4], r1[s][5], r1[s][6], r1[s][7]);
                                } else {
                                    dst[0] = make_float4(r2[s][0], r2[s][1], r2[s][2], r2[s][3]);
                                    dst[1] = make_float4(r2[s][4], r2[s][5], r2[s][6], r2[s][7]);
                                }
                            }
                        }
                        asm volatile("s_waitcnt lgkmcnt(0)" ::: "memory");
                        float xs = 0.f;
                        if (lane == 0) xs = np_sum_sq_128(&s_rbuf[wid][0]);
                        xs = __shfl(xs, 0);

                        const float* rb = &s_rbuf[wid][0];
                        float a0 = 0.f, a1 = 0.f, a2 = 0.f, a3 = 0.f;
#pragma unroll 8
                        for (int d = 0; d < DIM; ++d) {
                            float rv = rb[d];
                            const float* row = cbTk + (size_t)d * CB_SIZE;
                            a0 = fmaf(rv, row[0],   a0);
                            a1 = fmaf(rv, row[64],  a1);
                            a2 = fmaf(rv, row[128], a2);
                            a3 = fmaf(rv, row[192], a3);
                        }
                        float dd0, dd1, dd2, dd3;
                        {
#pragma clang fp contract(off)
                            float S0 = xs + esqk[lane];
                            float S1 = xs + esqk[lane + 64];
                            float S2 = xs + esqk[lane + 128];
                            float S3 = xs + esqk[lane + 192];
                            dd0 = S0 - 2.0f * a0;
                            dd1 = S1 - 2.0f * a1;
                            dd2 = S2 - 2.0f * a2;
                            dd3 = S3 - 2.0f * a3;
                        }
                        float bd = dd0; int bc = lane;
                        if (dd1 < bd) { bd = dd1; bc = lane + 64; }
                        if (dd2 < bd) { bd = dd2; bc = lane + 128; }
                        if (dd3 < bd) { bd = dd3; bc = lane + 192; }
#pragma unroll
                        for (int d = 1; d < 64; d <<= 1) {
                            float od = __shfl_xor(bd, d);
                            int   oc = __shfl_xor(bc, d);
                            if (od < bd || (od == bd && oc < bc)) { bd = od; bc = oc; }
                        }
                        if (lrow == srct) {
                            if (grp == 0) cmin1 = bc; else cmin2 = bc;
                        }
                    }
                }

                if (lane < 16) {
                    out_idx[(size_t)(tokw + lane) * NUM_CB + k] = (float)cmin1;
                    out_idx[(size_t)(tokw + 16 + lane) * NUM_CB + k] = (float)cmin2;
                }

                // residual update + loss (both groups)
                const float* ep1 = cbk + (size_t)cmin1 * DIM + 8 * lq;
                const float* ep2 = cbk + (size_t)cmin2 * DIM + 8 * lq;
                float l0 = 0.f, l1 = 0.f, l2 = 0.f, l3 = 0.f;
#pragma unroll
                for (int s = 0; s < 4; ++s) {
                    float4 ev0 = *reinterpret_cast<const float4*>(ep1 + 32 * s);
                    float4 ev1 = *reinterpret_cast<const float4*>(ep1 + 32 * s + 4);
                    float d0 = ev0.x - r1[s][0], d1 = ev0.y - r1[s][1];
                    float d2 = ev0.z - r1[s][2], d3 = ev0.w - r1[s][3];
                    float d4 = ev1.x - r1[s][4], d5 = ev1.y - r1[s][5];
                    float d6 = ev1.z - r1[s][6], d7 = ev1.w - r1[s][7];
                    l0 = fmaf(d0, d0, l0); l1 = fmaf(d1, d1, l1);
                    l2 = fmaf(d2, d2, l2); l3 = fmaf(d3, d3, l3);
                    l0 = fmaf(d4, d4, l0); l1 = fmaf(d5, d5, l1);
                    l2 = fmaf(d6, d6, l2); l3 = fmaf(d7, d7, l3);
                    r1[s][0] -= ev0.x; r1[s][1] -= ev0.y; r1[s][2] -= ev0.z; r1[s][3] -= ev0.w;
                    r1[s][4] -= ev1.x; r1[s][5] -= ev1.y; r1[s][6] -= ev1.z; r1[s][7] -= ev1.w;
                    float4 fv0 = *reinterpret_cast<const float4*>(ep2 + 32 * s);
                    float4 fv1 = *reinterpret_cast<const float4*>(ep2 + 32 * s + 4);
                    float e0 = fv0.x - r2[s][0], e1 = fv0.y - r2[s][1];
                    float e2 = fv0.z - r2[s][2], e3 = fv0.w - r2[s][3];
                    float e4 = fv1.x - r2[s][4], e5 = fv1.y - r2[s][5];
                    float e6 = fv1.z - r2[s][6], e7 = fv1.w - r2[s][7];
                    l0 = fmaf(e0, e0, l0); l1 = fmaf(e1, e1, l1);
                    l2 = fmaf(e2, e2, l2); l3 = fmaf(e3, e3, l3);
                    l0 = fmaf(e4, e4, l0); l1 = fmaf(e5, e5, l1);
                    l2 = fmaf(e6, e6, l2); l3 = fmaf(e7, e7, l3);
                    r2[s][0] -= fv0.x; r2[s][1] -= fv0.y; r2[s][2] -= fv0.z; r2[s][3] -= fv0.w;
                    r2[s][4] -= fv1.x; r2[s][5] -= fv1.y; r2[s][6] -= fv1.z; r2[s][7] -= fv1.w;
                }
                lsum += (double)((l0 + l1) + (l2 + l3));

                if (k < NUM_CB - 1) {   // fast re-split for next codebook
#pragma unroll
                    for (int s = 0; s < 4; ++s)
#pragma unroll
                        for (int i = 0; i < 8; ++i) {
                            unsigned short h1 = f2bf(r1[s][i]);
                            ah1[s][i] = (short)h1;
                            am1[s][i] = (short)f2bf(r1[s][i] - bf16_tof(h1));
                            unsigned short h2 = f2bf(r2[s][i]);
                            ah2[s][i] = (short)h2;
                            am2[s][i] = (short)f2bf(r2[s][i] - bf16_tof(h2));
                        }
                }
                // ============== end epilogue ===============================
            }

            asm volatile("s_waitcnt vmcnt(0)" ::: "memory");  // prefetch landed
            __syncthreads();                                  // buf[nb] free
        }
    }

    // ---- quantized = z - r_final (both groups) ----
    {
        const float* zp1 = z + (size_t)tok1 * DIM + 8 * lq;
        float* op1 = out_q + (size_t)tok1 * DIM + 8 * lq;
        const float* zp2 = z + (size_t)tok2 * DIM + 8 * lq;
        float* op2 = out_q + (size_t)tok2 * DIM + 8 * lq;
#pragma unroll
        for (int s = 0; s < 4; ++s) {
            float4 a = *reinterpret_cast<const float4*>(zp1 + 32 * s);
            float4 b = *reinterpret_cast<const float4*>(zp1 + 32 * s + 4);
            *reinterpret_cast<float4*>(op1 + 32 * s) =
                make_float4(a.x - r1[s][0], a.y - r1[s][1],
                            a.z - r1[s][2], a.w - r1[s][3]);
            *reinterpret_cast<float4*>(op1 + 32 * s + 4) =
                make_float4(b.x - r1[s][4], b.y - r1[s][5],
                            b.z - r1[s][6], b.w - r1[s][7]);
            float4 c = *reinterpret_cast<const float4*>(zp2 + 32 * s);
            float4 d = *reinterpret_cast<const float4*>(zp2 + 32 * s + 4);
            *reinterpret_cast<float4*>(op2 + 32 * s) =
                make_float4(c.x - r2[s][0], c.y - r2[s][1],
                            c.z - r2[s][2], c.w - r2[s][3]);
            *reinterpret_cast<float4*>(op2 + 32 * s + 4) =
                make_float4(d.x - r2[s][4], d.y - r2[s][5],
                            d.z - r2[s][6], d.w - r2[s][7]);
        }
    }

    // ---- loss reduction ----
    for (int off = 32; off > 0; off >>= 1)
        lsum += __shfl_down(lsum, off, 64);
    if (lane == 0) s_wsum[wid] = lsum;
    __syncthreads();
    if (tid == 0) {
        double t = 0.0;
#pragma unroll
        for (int w = 0; w < 4; ++w) t += s_wsum[w];
        atomicAdd(loss_acc, t);
    }
}

__global__ void rvq_finalize_kernel(const double* __restrict__ loss_acc,
                                    float* __restrict__ out_loss) {
    out_loss[0] = (float)(1.25 * loss_acc[0] / (double)Q_ELEMS);
}

extern "C" void kernel_launch(void* const* d_in, const int* in_sizes, int n_in,
                              void* d_out, int out_size, void* d_ws, size_t ws_size,
                              hipStream_t stream) {
    const float* z  = (const float*)d_in[0];
    const float* cb = (const float*)d_in[1];

    float* out_q    = (float*)d_out;
    float* out_idx  = out_q + Q_ELEMS;
    float* out_loss = out_idx + I_ELEMS;

    double* loss_acc = (double*)d_ws;
    float*  esq      = (float*)((char*)d_ws + 256);              // 8 KB
    bf16x8* g_img    = (bf16x8*)((char*)d_ws + 65536);           // 1 MB
    float*  cbT      = (float*)((char*)d_ws + 65536 + 1048576);  // 1 MB

    hipMemsetAsync(loss_acc, 0, sizeof(double), stream);
    rvq_esq_kernel<<<(NUM_CB * CB_SIZE + 255) / 256, 256, 0, stream>>>(cb, esq);
    rvq_split_kernel<<<(NUM_CB * CB_SIZE * 16 + 255) / 256, 256, 0, stream>>>(
        cb, g_img);
    rvq_transpose_kernel<<<(NUM_CB * DIM * CB_SIZE + 255) / 256, 256, 0,
                           stream>>>(cb, cbT);
    rvq_mfma_kernel<<<BT / 128, 256, 0, stream>>>(z, cb, cbT, esq, g_img,
                                                  out_q, out_idx, loss_acc);
    rvq_finalize_kernel<<<1, 1, 0, stream>>>(loss_acc, out_loss);
}

// Round 17
// 1017.770 us; speedup vs baseline: 4.4576x; 4.4576x over previous
//
#include <hip/hip_runtime.h>
#include <hip/hip_bf16.h>
#include <math.h>
#include <float.h>

#define NUM_CB 8
#define CB_SIZE 256
#define DIM 128
#define BT (16 * 16384)                  // 262144 tokens
#define Q_ELEMS ((size_t)BT * DIM)       // 33554432
#define I_ELEMS ((size_t)BT * NUM_CB)    // 2097152

#define TC 64                            // candidates per streamed tile
#define TILES_PER_CB (CB_SIZE / TC)      // 4
#define TILE_BYTES 32768                 // 2 planes x 64 cand x 16 slots x 16B

// Pass-A ambiguity margin (validated rounds 6-16). Do not shrink.
#define MARGIN_A 1.5e-4f

typedef short  bf16x8 __attribute__((ext_vector_type(8)));
typedef float  f32x16 __attribute__((ext_vector_type(16)));

__device__ __forceinline__ unsigned short bf16_rne(float f) {
    unsigned int u = __float_as_uint(f);
    u = u + 0x7FFFu + ((u >> 16) & 1u);
    return (unsigned short)(u >> 16);
}
__device__ __forceinline__ float bf16_tof(unsigned short h) {
    return __uint_as_float(((unsigned int)h) << 16);
}
__device__ __forceinline__ unsigned short f2bf(float f) {
    __hip_bfloat16 h = __float2bfloat16(f);
    return *reinterpret_cast<unsigned short*>(&h);
}

// ---------------------------------------------------------------------------
// VALIDATED np emulation (rounds 6-16): pairwise-8 sum-of-squares, no FMA.
// ---------------------------------------------------------------------------
__device__ __forceinline__ float np_sum_sq_128(const float* a) {
#pragma clang fp contract(off)
    float r0 = 0.f, r1 = 0.f, r2 = 0.f, r3 = 0.f,
          r4 = 0.f, r5 = 0.f, r6 = 0.f, r7 = 0.f;
#pragma unroll
    for (int i = 0; i < DIM; i += 8) {
        r0 = r0 + a[i + 0] * a[i + 0];
        r1 = r1 + a[i + 1] * a[i + 1];
        r2 = r2 + a[i + 2] * a[i + 2];
        r3 = r3 + a[i + 3] * a[i + 3];
        r4 = r4 + a[i + 4] * a[i + 4];
        r5 = r5 + a[i + 5] * a[i + 5];
        r6 = r6 + a[i + 6] * a[i + 6];
        r7 = r7 + a[i + 7] * a[i + 7];
    }
    return ((r0 + r1) + (r2 + r3)) + ((r4 + r5) + (r6 + r7));
}

__global__ void rvq_esq_kernel(const float* __restrict__ cb,
                               float* __restrict__ esq) {
    int i = blockIdx.x * blockDim.x + threadIdx.x;   // 0 .. 2047
    if (i >= NUM_CB * CB_SIZE) return;
    esq[i] = np_sum_sq_128(cb + (size_t)i * DIM);
}

// Per-lane packed esq for the 32x32 C layout:
// esq_pk[((k*8+til)*64+lane)*16+reg] = esq[k][til*32 + (reg&3)+8*(reg>>2)+4*(lane>>5)]
__global__ void rvq_esqpk_kernel(const float* __restrict__ esq,
                                 float* __restrict__ esq_pk) {
    int idx = blockIdx.x * blockDim.x + threadIdx.x;   // 0 .. 65535
    if (idx >= NUM_CB * 8 * 64 * 16) return;
    int reg  = idx & 15;
    int lane = (idx >> 4) & 63;
    int til  = (idx >> 10) & 7;
    int k    = idx >> 13;
    esq_pk[idx] = esq[k * CB_SIZE + til * 32 +
                      (reg & 3) + 8 * (reg >> 2) + 4 * (lane >> 5)];
}

// Transposed f32 codebook for coalesced Pass-B reads: cbT[k][d][c]
__global__ void rvq_transpose_kernel(const float* __restrict__ cb,
                                     float* __restrict__ cbT) {
    int idx = blockIdx.x * blockDim.x + threadIdx.x;   // 0 .. 262143
    if (idx >= NUM_CB * DIM * CB_SIZE) return;
    int c = idx & (CB_SIZE - 1);
    int d = (idx >> 8) & (DIM - 1);
    int k = idx >> 15;
    cbT[idx] = cb[((size_t)(k * CB_SIZE + c)) * DIM + d];
}

// ---------------------------------------------------------------------------
// Precompute merged bf16 hi|lo image in the swizzled LDS layout (validated):
// img[t*2048 + plane*1024 + cand*16 + (slot ^ (cand&15))], t = k*4 + T,
// codeword = t*64 + cand. Identical to rounds 12-16 (read-compatible with
// both the 16x16 and 32x32 fragment fetch patterns).
// ---------------------------------------------------------------------------
__global__ void rvq_split_kernel(const float* __restrict__ cb,
                                 bf16x8* __restrict__ g_img) {
    int idx = blockIdx.x * blockDim.x + threadIdx.x;   // 0 .. 32767
    if (idx >= NUM_CB * CB_SIZE * 16) return;
    int slot = idx & 15;
    int cand = (idx >> 4) & (TC - 1);
    int t    = idx >> 10;                 // 0..31
    const float* src = cb + ((size_t)t * TC + cand) * DIM + slot * 8;
    float4 a = *reinterpret_cast<const float4*>(src);
    float4 b = *reinterpret_cast<const float4*>(src + 4);
    float e[8] = {a.x, a.y, a.z, a.w, b.x, b.y, b.z, b.w};
    bf16x8 eh, el;
#pragma unroll
    for (int i = 0; i < 8; ++i) {
        unsigned short h = bf16_rne(e[i]);
        float rem = e[i] - bf16_tof(h);
        eh[i] = (short)h;
        el[i] = (short)bf16_rne(rem);
    }
    int ds = slot ^ (cand & 15);
    g_img[(size_t)t * 2048 + cand * 16 + ds]        = eh;
    g_img[(size_t)t * 2048 + 1024 + cand * 16 + ds] = el;
}

// DMA one 32KB tile into LDS buffer: 8 x global_load_lds(16B) per wave (4 wv).
__device__ __forceinline__ void stage_tile(const bf16x8* __restrict__ g_img,
                                           bf16x8 (*s_buf)[2048],
                                           int t, int nb, int wid, int lane) {
    const char* gt = (const char*)g_img + (size_t)t * TILE_BYTES
                     + wid * 8192 + lane * 16;
    const char* lb = (const char*)(&s_buf[nb][0]) + wid * 8192;  // wave-uniform
#pragma unroll
    for (int c = 0; c < 8; ++c) {
        __builtin_amdgcn_global_load_lds(
            (const __attribute__((address_space(1))) unsigned int*)(gt + c * 1024),
            (__attribute__((address_space(3))) unsigned int*)(lb + c * 1024),
            16, 0, 0);
    }
}

// ---------------------------------------------------------------------------
// Main fused kernel: 128 tokens/block (4 waves x 32 tokens), residual in
// VGPRs. mfma_f32_32x32x16_bf16, swapped operands (A = codebook, B =
// residual): D[cand][token], col=lane&31=token, row=(reg&3)+8*(reg>>2)
// +4*(lane>>5). Lane owns token lane&31, dims {16s + 8*(lane>>5) + i}.
// LDS reads per token HALVED vs the 16x16 path (A-frags shared by 32 tokens).
// ---------------------------------------------------------------------------
__global__ __launch_bounds__(256) void rvq_mfma_kernel(
    const float* __restrict__ z,
    const float* __restrict__ cb,
    const float* __restrict__ cbT,
    const float* __restrict__ esq,
    const float* __restrict__ esq_pk,
    const bf16x8* __restrict__ g_img,
    float* __restrict__ out_q,
    float* __restrict__ out_idx,
    double* __restrict__ loss_acc) {

    __shared__ bf16x8 s_buf[2][2048];                // 2 x 32KB double buffer
    __shared__ __align__(16) float s_rbuf[4][DIM];   // per-wave passB residual
    __shared__ double s_wsum[4];

    const int tid  = threadIdx.x;
    const int wid  = tid >> 6;
    const int lane = tid & 63;
    const int tk   = lane & 31;       // token-in-wave / cand-in-subtile
    const int half = lane >> 5;       // k-half selector
    const int tokw = blockIdx.x * 128 + wid * 32;
    const int tok  = tokw + tk;

    // ---- residual: r[s][i] = z[tok][16*s + 8*half + i] ----
    float r[8][8];
    {
        const float* zp = z + (size_t)tok * DIM + 8 * half;
#pragma unroll
        for (int s = 0; s < 8; ++s) {
            float4 a = *reinterpret_cast<const float4*>(zp + 16 * s);
            float4 b = *reinterpret_cast<const float4*>(zp + 16 * s + 4);
            r[s][0] = a.x; r[s][1] = a.y; r[s][2] = a.z; r[s][3] = a.w;
            r[s][4] = b.x; r[s][5] = b.y; r[s][6] = b.z; r[s][7] = b.w;
        }
    }

    // ---- bf16 hi/mid splits (HW RNE; margin-covered) ----
    bf16x8 rh[8], rm[8];
#pragma unroll
    for (int s = 0; s < 8; ++s)
#pragma unroll
        for (int i = 0; i < 8; ++i) {
            unsigned short h = f2bf(r[s][i]);
            rh[s][i] = (short)h;
            rm[s][i] = (short)f2bf(r[s][i] - bf16_tof(h));
        }

    double lsum = 0.0;

    // prologue: stage tile 0
    stage_tile(g_img, s_buf, 0, 0, wid, lane);
    asm volatile("s_waitcnt vmcnt(0)" ::: "memory");
    __syncthreads();

    for (int k = 0; k < NUM_CB; ++k) {
        const float* esqk = esq + k * CB_SIZE;
        const float* cbk  = cb  + (size_t)k * CB_SIZE * DIM;
        const float* cbTk = cbT + (size_t)k * DIM * CB_SIZE + lane;

        float m1 = FLT_MAX, m2 = FLT_MAX;
        int   i1 = 0x7fffffff;

#pragma unroll
        for (int T = 0; T < TILES_PER_CB; ++T) {
            const int t  = k * TILES_PER_CB + T;
            const int nb = T & 1;
            if (k < NUM_CB - 1 || T < TILES_PER_CB - 1)
                stage_tile(g_img, s_buf, t + 1, nb ^ 1, wid, lane);

#pragma unroll
            for (int u = 0; u < 2; ++u) {         // 32-candidate subtiles
                const int til = T * 2 + u;        // 0..7 within cb
                const int cand_img = u * 32 + tk; // cand row in staged tile
                // per-lane esq for this subtile's C layout
                float eq[16];
                {
                    const float4* ep4 = reinterpret_cast<const float4*>(
                        esq_pk + (((size_t)(k * 8 + til) * 64 + lane) * 16));
#pragma unroll
                    for (int j = 0; j < 4; ++j) {
                        float4 v = ep4[j];
                        eq[4 * j + 0] = v.x; eq[4 * j + 1] = v.y;
                        eq[4 * j + 2] = v.z; eq[4 * j + 3] = v.w;
                    }
                }
                f32x16 acca = {0.f, 0.f, 0.f, 0.f, 0.f, 0.f, 0.f, 0.f,
                               0.f, 0.f, 0.f, 0.f, 0.f, 0.f, 0.f, 0.f};
                f32x16 accb = acca;
#pragma unroll
                for (int s = 0; s < 8; ++s) {     // K = 128 in 8 steps of 16
                    const int ls = (2 * s + half) ^ (tk & 15);
                    bf16x8 eh = s_buf[nb][cand_img * 16 + ls];
                    bf16x8 el = s_buf[nb][1024 + cand_img * 16 + ls];
                    acca = __builtin_amdgcn_mfma_f32_32x32x16_bf16(eh, rh[s], acca, 0, 0, 0);
                    accb = __builtin_amdgcn_mfma_f32_32x32x16_bf16(eh, rm[s], accb, 0, 0, 0);
                    accb = __builtin_amdgcn_mfma_f32_32x32x16_bf16(el, rh[s], accb, 0, 0, 0);
                }
                // scores: cand = til*32 + (reg&3)+8*(reg>>2)+4*half (ascending)
#pragma unroll
                for (int reg = 0; reg < 16; ++reg) {
                    const int c = til * 32 + (reg & 3) + 8 * (reg >> 2) + 4 * half;
                    float sc = fmaf(-2.0f, acca[reg] + accb[reg], eq[reg]);
                    m2 = __builtin_amdgcn_fmed3f(m1, m2, sc);
                    if (sc < m1) { i1 = c; }
                    m1 = fminf(m1, sc);
                }
            }

            if (T == TILES_PER_CB - 1) {
                // ============== per-codebook epilogue (wave-internal) ======
                // pair lex top-2 reduce: token's scores live in lanes {t,t+32}
                {
                    float o1 = __shfl_xor(m1, 32);
                    float o2 = __shfl_xor(m2, 32);
                    int   oi = __shfl_xor(i1, 32);
                    bool ow = (o1 < m1) || (o1 == m1 && oi < i1);
                    float lo = ow ? m1 : o1;
                    m1 = ow ? o1 : m1;
                    i1 = ow ? oi : i1;
                    m2 = fminf(fminf(m2, o2), lo);
                }
                int cmin = i1;

                // Pass B (rare): exact np argmin, coalesced cbT (validated)
                bool amb = !(m2 - m1 > MARGIN_A);
                unsigned long long mask = __ballot(amb && lane < 32);
                while (mask) {
                    int srct = __ffsll(mask) - 1;
                    mask &= mask - 1;
                    if (tk == srct) {   // both halves write their 64 dims
#pragma unroll
                        for (int s = 0; s < 8; ++s) {
                            float* dst = &s_rbuf[wid][16 * s + 8 * half];
                            *reinterpret_cast<float4*>(dst) =
                                make_float4(r[s][0], r[s][1], r[s][2], r[s][3]);
                            *reinterpret_cast<float4*>(dst + 4) =
                                make_float4(r[s][4], r[s][5], r[s][6], r[s][7]);
                        }
                    }
                    asm volatile("s_waitcnt lgkmcnt(0)" ::: "memory");
                    float xs = 0.f;
                    if (lane == 0) xs = np_sum_sq_128(&s_rbuf[wid][0]);
                    xs = __shfl(xs, 0);

                    const float* rb = &s_rbuf[wid][0];
                    float a0 = 0.f, a1 = 0.f, a2 = 0.f, a3 = 0.f;
#pragma unroll 8
                    for (int d = 0; d < DIM; ++d) {
                        float rv = rb[d];
                        const float* row = cbTk + (size_t)d * CB_SIZE;
                        a0 = fmaf(rv, row[0],   a0);
                        a1 = fmaf(rv, row[64],  a1);
                        a2 = fmaf(rv, row[128], a2);
                        a3 = fmaf(rv, row[192], a3);
                    }
                    float dd0, dd1, dd2, dd3;
                    {
#pragma clang fp contract(off)
                        float S0 = xs + esqk[lane];
                        float S1 = xs + esqk[lane + 64];
                        float S2 = xs + esqk[lane + 128];
                        float S3 = xs + esqk[lane + 192];
                        dd0 = S0 - 2.0f * a0;
                        dd1 = S1 - 2.0f * a1;
                        dd2 = S2 - 2.0f * a2;
                        dd3 = S3 - 2.0f * a3;
                    }
                    float bd = dd0; int bc = lane;
                    if (dd1 < bd) { bd = dd1; bc = lane + 64; }
                    if (dd2 < bd) { bd = dd2; bc = lane + 128; }
                    if (dd3 < bd) { bd = dd3; bc = lane + 192; }
#pragma unroll
                    for (int d = 1; d < 64; d <<= 1) {
                        float od = __shfl_xor(bd, d);
                        int   oc = __shfl_xor(bc, d);
                        if (od < bd || (od == bd && oc < bc)) { bd = od; bc = oc; }
                    }
                    if (tk == srct) cmin = bc;
                }

                if (lane < 32)
                    out_idx[(size_t)(tokw + lane) * NUM_CB + k] = (float)cmin;

                // residual update + loss (lane's 64 dims)
                const float* ep = cbk + (size_t)cmin * DIM + 8 * half;
                float l0 = 0.f, l1 = 0.f, l2 = 0.f, l3 = 0.f;
#pragma unroll
                for (int s = 0; s < 8; ++s) {
                    float4 ev0 = *reinterpret_cast<const float4*>(ep + 16 * s);
                    float4 ev1 = *reinterpret_cast<const float4*>(ep + 16 * s + 4);
                    float d0 = ev0.x - r[s][0], d1 = ev0.y - r[s][1];
                    float d2 = ev0.z - r[s][2], d3 = ev0.w - r[s][3];
                    float d4 = ev1.x - r[s][4], d5 = ev1.y - r[s][5];
                    float d6 = ev1.z - r[s][6], d7 = ev1.w - r[s][7];
                    l0 = fmaf(d0, d0, l0); l1 = fmaf(d1, d1, l1);
                    l2 = fmaf(d2, d2, l2); l3 = fmaf(d3, d3, l3);
                    l0 = fmaf(d4, d4, l0); l1 = fmaf(d5, d5, l1);
                    l2 = fmaf(d6, d6, l2); l3 = fmaf(d7, d7, l3);
                    r[s][0] -= ev0.x; r[s][1] -= ev0.y; r[s][2] -= ev0.z; r[s][3] -= ev0.w;
                    r[s][4] -= ev1.x; r[s][5] -= ev1.y; r[s][6] -= ev1.z; r[s][7] -= ev1.w;
                }
                lsum += (double)((l0 + l1) + (l2 + l3));

                if (k < NUM_CB - 1) {   // fast re-split for next codebook
#pragma unroll
                    for (int s = 0; s < 8; ++s)
#pragma unroll
                        for (int i = 0; i < 8; ++i) {
                            unsigned short h = f2bf(r[s][i]);
                            rh[s][i] = (short)h;
                            rm[s][i] = (short)f2bf(r[s][i] - bf16_tof(h));
                        }
                }
                // ============== end epilogue ===============================
            }

            asm volatile("s_waitcnt vmcnt(0)" ::: "memory");  // prefetch landed
            __syncthreads();                                  // buf[nb] free
        }
    }

    // ---- quantized = z - r_final (lane's 64 dims) ----
    {
        const float* zp = z + (size_t)tok * DIM + 8 * half;
        float* op = out_q + (size_t)tok * DIM + 8 * half;
#pragma unroll
        for (int s = 0; s < 8; ++s) {
            float4 a = *reinterpret_cast<const float4*>(zp + 16 * s);
            float4 b = *reinterpret_cast<const float4*>(zp + 16 * s + 4);
            *reinterpret_cast<float4*>(op + 16 * s) =
                make_float4(a.x - r[s][0], a.y - r[s][1],
                            a.z - r[s][2], a.w - r[s][3]);
            *reinterpret_cast<float4*>(op + 16 * s + 4) =
                make_float4(b.x - r[s][4], b.y - r[s][5],
                            b.z - r[s][6], b.w - r[s][7]);
        }
    }

    // ---- loss reduction ----
    for (int off = 32; off > 0; off >>= 1)
        lsum += __shfl_down(lsum, off, 64);
    if (lane == 0) s_wsum[wid] = lsum;
    __syncthreads();
    if (tid == 0) {
        double tt = 0.0;
#pragma unroll
        for (int w = 0; w < 4; ++w) tt += s_wsum[w];
        atomicAdd(loss_acc, tt);
    }
}

__global__ void rvq_finalize_kernel(const double* __restrict__ loss_acc,
                                    float* __restrict__ out_loss) {
    out_loss[0] = (float)(1.25 * loss_acc[0] / (double)Q_ELEMS);
}

extern "C" void kernel_launch(void* const* d_in, const int* in_sizes, int n_in,
                              void* d_out, int out_size, void* d_ws, size_t ws_size,
                              hipStream_t stream) {
    const float* z  = (const float*)d_in[0];
    const float* cb = (const float*)d_in[1];

    float* out_q    = (float*)d_out;
    float* out_idx  = out_q + Q_ELEMS;
    float* out_loss = out_idx + I_ELEMS;

    double* loss_acc = (double*)d_ws;
    float*  esq      = (float*)((char*)d_ws + 256);               // 8 KB
    float*  esq_pk   = (float*)((char*)d_ws + 16384);             // 256 KB
    bf16x8* g_img    = (bf16x8*)((char*)d_ws + 294912);           // 1 MB
    float*  cbT      = (float*)((char*)d_ws + 294912 + 1048576);  // 1 MB

    hipMemsetAsync(loss_acc, 0, sizeof(double), stream);
    rvq_esq_kernel<<<(NUM_CB * CB_SIZE + 255) / 256, 256, 0, stream>>>(cb, esq);
    rvq_esqpk_kernel<<<(NUM_CB * 8 * 64 * 16 + 255) / 256, 256, 0, stream>>>(
        esq, esq_pk);
    rvq_split_kernel<<<(NUM_CB * CB_SIZE * 16 + 255) / 256, 256, 0, stream>>>(
        cb, g_img);
    rvq_transpose_kernel<<<(NUM_CB * DIM * CB_SIZE + 255) / 256, 256, 0,
                           stream>>>(cb, cbT);
    rvq_mfma_kernel<<<BT / 128, 256, 0, stream>>>(z, cb, cbT, esq, esq_pk,
                                                  g_img, out_q, out_idx,
                                                  loss_acc);
    rvq_finalize_kernel<<<1, 1, 0, stream>>>(loss_acc, out_loss);
}

// Round 18
// 1013.923 us; speedup vs baseline: 4.4745x; 1.0038x over previous
//
#include <hip/hip_runtime.h>
#include <hip/hip_bf16.h>
#include <math.h>
#include <float.h>

#define NUM_CB 8
#define CB_SIZE 256
#define DIM 128
#define BT (16 * 16384)                  // 262144 tokens
#define Q_ELEMS ((size_t)BT * DIM)       // 33554432
#define I_ELEMS ((size_t)BT * NUM_CB)    // 2097152

#define TC 64                            // candidates per streamed tile
#define TILES_PER_CB (CB_SIZE / TC)      // 4
#define TILE_BYTES 32768                 // 2 planes x 64 cand x 16 slots x 16B

// Pass-A ambiguity margin. With the 4-product split (errA ~5e-6) the
// rigorous need is ~3.8e-5 (errRef_diff 3.3e-5 + errA); 8e-5 = 2.1x safety
// (same safety class as the r6-validated 1.5e-4 against errA=3e-5).
#define MARGIN_A 8e-5f

typedef short  bf16x8 __attribute__((ext_vector_type(8)));
typedef float  f32x16 __attribute__((ext_vector_type(16)));

__device__ __forceinline__ unsigned short bf16_rne(float f) {
    unsigned int u = __float_as_uint(f);
    u = u + 0x7FFFu + ((u >> 16) & 1u);
    return (unsigned short)(u >> 16);
}
__device__ __forceinline__ float bf16_tof(unsigned short h) {
    return __uint_as_float(((unsigned int)h) << 16);
}
__device__ __forceinline__ unsigned short f2bf(float f) {
    __hip_bfloat16 h = __float2bfloat16(f);
    return *reinterpret_cast<unsigned short*>(&h);
}

// ---------------------------------------------------------------------------
// VALIDATED np emulation (rounds 6-17): pairwise-8 sum-of-squares, no FMA.
// ---------------------------------------------------------------------------
__device__ __forceinline__ float np_sum_sq_128(const float* a) {
#pragma clang fp contract(off)
    float r0 = 0.f, r1 = 0.f, r2 = 0.f, r3 = 0.f,
          r4 = 0.f, r5 = 0.f, r6 = 0.f, r7 = 0.f;
#pragma unroll
    for (int i = 0; i < DIM; i += 8) {
        r0 = r0 + a[i + 0] * a[i + 0];
        r1 = r1 + a[i + 1] * a[i + 1];
        r2 = r2 + a[i + 2] * a[i + 2];
        r3 = r3 + a[i + 3] * a[i + 3];
        r4 = r4 + a[i + 4] * a[i + 4];
        r5 = r5 + a[i + 5] * a[i + 5];
        r6 = r6 + a[i + 6] * a[i + 6];
        r7 = r7 + a[i + 7] * a[i + 7];
    }
    return ((r0 + r1) + (r2 + r3)) + ((r4 + r5) + (r6 + r7));
}

__global__ void rvq_esq_kernel(const float* __restrict__ cb,
                               float* __restrict__ esq) {
    int i = blockIdx.x * blockDim.x + threadIdx.x;   // 0 .. 2047
    if (i >= NUM_CB * CB_SIZE) return;
    esq[i] = np_sum_sq_128(cb + (size_t)i * DIM);
}

// Per-lane packed esq for the 32x32 C layout:
// esq_pk[((k*8+til)*64+lane)*16+reg] = esq[k][til*32 + (reg&3)+8*(reg>>2)+4*(lane>>5)]
__global__ void rvq_esqpk_kernel(const float* __restrict__ esq,
                                 float* __restrict__ esq_pk) {
    int idx = blockIdx.x * blockDim.x + threadIdx.x;   // 0 .. 65535
    if (idx >= NUM_CB * 8 * 64 * 16) return;
    int reg  = idx & 15;
    int lane = (idx >> 4) & 63;
    int til  = (idx >> 10) & 7;
    int k    = idx >> 13;
    esq_pk[idx] = esq[k * CB_SIZE + til * 32 +
                      (reg & 3) + 8 * (reg >> 2) + 4 * (lane >> 5)];
}

// Transposed f32 codebook for coalesced Pass-B reads: cbT[k][d][c]
__global__ void rvq_transpose_kernel(const float* __restrict__ cb,
                                     float* __restrict__ cbT) {
    int idx = blockIdx.x * blockDim.x + threadIdx.x;   // 0 .. 262143
    if (idx >= NUM_CB * DIM * CB_SIZE) return;
    int c = idx & (CB_SIZE - 1);
    int d = (idx >> 8) & (DIM - 1);
    int k = idx >> 15;
    cbT[idx] = cb[((size_t)(k * CB_SIZE + c)) * DIM + d];
}

// ---------------------------------------------------------------------------
// Precompute merged bf16 hi|lo image in the swizzled LDS layout (validated):
// img[t*2048 + plane*1024 + cand*16 + (slot ^ (cand&15))], t = k*4 + T,
// codeword = t*64 + cand.
// ---------------------------------------------------------------------------
__global__ void rvq_split_kernel(const float* __restrict__ cb,
                                 bf16x8* __restrict__ g_img) {
    int idx = blockIdx.x * blockDim.x + threadIdx.x;   // 0 .. 32767
    if (idx >= NUM_CB * CB_SIZE * 16) return;
    int slot = idx & 15;
    int cand = (idx >> 4) & (TC - 1);
    int t    = idx >> 10;                 // 0..31
    const float* src = cb + ((size_t)t * TC + cand) * DIM + slot * 8;
    float4 a = *reinterpret_cast<const float4*>(src);
    float4 b = *reinterpret_cast<const float4*>(src + 4);
    float e[8] = {a.x, a.y, a.z, a.w, b.x, b.y, b.z, b.w};
    bf16x8 eh, el;
#pragma unroll
    for (int i = 0; i < 8; ++i) {
        unsigned short h = bf16_rne(e[i]);
        float rem = e[i] - bf16_tof(h);
        eh[i] = (short)h;
        el[i] = (short)bf16_rne(rem);
    }
    int ds = slot ^ (cand & 15);
    g_img[(size_t)t * 2048 + cand * 16 + ds]        = eh;
    g_img[(size_t)t * 2048 + 1024 + cand * 16 + ds] = el;
}

// DMA one 32KB tile into LDS buffer: 8 x global_load_lds(16B) per wave (4 wv).
__device__ __forceinline__ void stage_tile(const bf16x8* __restrict__ g_img,
                                           bf16x8 (*s_buf)[2048],
                                           int t, int nb, int wid, int lane) {
    const char* gt = (const char*)g_img + (size_t)t * TILE_BYTES
                     + wid * 8192 + lane * 16;
    const char* lb = (const char*)(&s_buf[nb][0]) + wid * 8192;  // wave-uniform
#pragma unroll
    for (int c = 0; c < 8; ++c) {
        __builtin_amdgcn_global_load_lds(
            (const __attribute__((address_space(1))) unsigned int*)(gt + c * 1024),
            (__attribute__((address_space(3))) unsigned int*)(lb + c * 1024),
            16, 0, 0);
    }
}

// ---------------------------------------------------------------------------
// Main fused kernel: 128 tokens/block (4 waves x 32 tokens), residual in
// VGPRs. mfma_f32_32x32x16_bf16, swapped operands (A = codebook, B =
// residual): D[cand][token], col=lane&31=token, row=(reg&3)+8*(reg>>2)
// +4*(lane>>5). Lane owns token lane&31, dims {16s + 8*(lane>>5) + i}.
// Pass A uses the FULL 4-product split: (eh+el)*(rh+rm) across two balanced
// 16-deep acc chains -> errA ~5e-6, enabling MARGIN_A = 8e-5.
// ---------------------------------------------------------------------------
__global__ __launch_bounds__(256) void rvq_mfma_kernel(
    const float* __restrict__ z,
    const float* __restrict__ cb,
    const float* __restrict__ cbT,
    const float* __restrict__ esq,
    const float* __restrict__ esq_pk,
    const bf16x8* __restrict__ g_img,
    float* __restrict__ out_q,
    float* __restrict__ out_idx,
    double* __restrict__ loss_acc) {

    __shared__ bf16x8 s_buf[2][2048];                // 2 x 32KB double buffer
    __shared__ __align__(16) float s_rbuf[4][DIM];   // per-wave passB residual
    __shared__ double s_wsum[4];

    const int tid  = threadIdx.x;
    const int wid  = tid >> 6;
    const int lane = tid & 63;
    const int tk   = lane & 31;       // token-in-wave / cand-in-subtile
    const int half = lane >> 5;       // k-half selector
    const int tokw = blockIdx.x * 128 + wid * 32;
    const int tok  = tokw + tk;

    // ---- residual: r[s][i] = z[tok][16*s + 8*half + i] ----
    float r[8][8];
    {
        const float* zp = z + (size_t)tok * DIM + 8 * half;
#pragma unroll
        for (int s = 0; s < 8; ++s) {
            float4 a = *reinterpret_cast<const float4*>(zp + 16 * s);
            float4 b = *reinterpret_cast<const float4*>(zp + 16 * s + 4);
            r[s][0] = a.x; r[s][1] = a.y; r[s][2] = a.z; r[s][3] = a.w;
            r[s][4] = b.x; r[s][5] = b.y; r[s][6] = b.z; r[s][7] = b.w;
        }
    }

    // ---- bf16 hi/mid splits (HW RNE; margin-covered) ----
    bf16x8 rh[8], rm[8];
#pragma unroll
    for (int s = 0; s < 8; ++s)
#pragma unroll
        for (int i = 0; i < 8; ++i) {
            unsigned short h = f2bf(r[s][i]);
            rh[s][i] = (short)h;
            rm[s][i] = (short)f2bf(r[s][i] - bf16_tof(h));
        }

    double lsum = 0.0;

    // prologue: stage tile 0
    stage_tile(g_img, s_buf, 0, 0, wid, lane);
    asm volatile("s_waitcnt vmcnt(0)" ::: "memory");
    __syncthreads();

    for (int k = 0; k < NUM_CB; ++k) {
        const float* esqk = esq + k * CB_SIZE;
        const float* cbk  = cb  + (size_t)k * CB_SIZE * DIM;
        const float* cbTk = cbT + (size_t)k * DIM * CB_SIZE + lane;

        float m1 = FLT_MAX, m2 = FLT_MAX;
        int   i1 = 0x7fffffff;

#pragma unroll
        for (int T = 0; T < TILES_PER_CB; ++T) {
            const int t  = k * TILES_PER_CB + T;
            const int nb = T & 1;
            if (k < NUM_CB - 1 || T < TILES_PER_CB - 1)
                stage_tile(g_img, s_buf, t + 1, nb ^ 1, wid, lane);

#pragma unroll
            for (int u = 0; u < 2; ++u) {         // 32-candidate subtiles
                const int til = T * 2 + u;        // 0..7 within cb
                const int cand_img = u * 32 + tk; // cand row in staged tile
                // per-lane esq for this subtile's C layout
                float eq[16];
                {
                    const float4* ep4 = reinterpret_cast<const float4*>(
                        esq_pk + (((size_t)(k * 8 + til) * 64 + lane) * 16));
#pragma unroll
                    for (int j = 0; j < 4; ++j) {
                        float4 v = ep4[j];
                        eq[4 * j + 0] = v.x; eq[4 * j + 1] = v.y;
                        eq[4 * j + 2] = v.z; eq[4 * j + 3] = v.w;
                    }
                }
                f32x16 acca = {0.f, 0.f, 0.f, 0.f, 0.f, 0.f, 0.f, 0.f,
                               0.f, 0.f, 0.f, 0.f, 0.f, 0.f, 0.f, 0.f};
                f32x16 accb = acca;
#pragma unroll
                for (int s = 0; s < 8; ++s) {     // K = 128 in 8 steps of 16
                    const int ls = (2 * s + half) ^ (tk & 15);
                    bf16x8 eh = s_buf[nb][cand_img * 16 + ls];
                    bf16x8 el = s_buf[nb][1024 + cand_img * 16 + ls];
                    // full 4-product split, balanced 2-per-step chains
                    acca = __builtin_amdgcn_mfma_f32_32x32x16_bf16(eh, rh[s], acca, 0, 0, 0);
                    accb = __builtin_amdgcn_mfma_f32_32x32x16_bf16(eh, rm[s], accb, 0, 0, 0);
                    accb = __builtin_amdgcn_mfma_f32_32x32x16_bf16(el, rh[s], accb, 0, 0, 0);
                    acca = __builtin_amdgcn_mfma_f32_32x32x16_bf16(el, rm[s], acca, 0, 0, 0);
                }
                // scores: cand = til*32 + (reg&3)+8*(reg>>2)+4*half (ascending)
#pragma unroll
                for (int reg = 0; reg < 16; ++reg) {
                    const int c = til * 32 + (reg & 3) + 8 * (reg >> 2) + 4 * half;
                    float sc = fmaf(-2.0f, acca[reg] + accb[reg], eq[reg]);
                    m2 = __builtin_amdgcn_fmed3f(m1, m2, sc);
                    if (sc < m1) { i1 = c; }
                    m1 = fminf(m1, sc);
                }
            }

            if (T == TILES_PER_CB - 1) {
                // ============== per-codebook epilogue (wave-internal) ======
                // pair lex top-2 reduce: token's scores live in lanes {t,t+32}
                {
                    float o1 = __shfl_xor(m1, 32);
                    float o2 = __shfl_xor(m2, 32);
                    int   oi = __shfl_xor(i1, 32);
                    bool ow = (o1 < m1) || (o1 == m1 && oi < i1);
                    float lo = ow ? m1 : o1;
                    m1 = ow ? o1 : m1;
                    i1 = ow ? oi : i1;
                    m2 = fminf(fminf(m2, o2), lo);
                }
                int cmin = i1;

                // Pass B (rare): exact np argmin, coalesced cbT (validated)
                bool amb = !(m2 - m1 > MARGIN_A);
                unsigned long long mask = __ballot(amb && lane < 32);
                while (mask) {
                    int srct = __ffsll(mask) - 1;
                    mask &= mask - 1;
                    if (tk == srct) {   // both halves write their 64 dims
#pragma unroll
                        for (int s = 0; s < 8; ++s) {
                            float* dst = &s_rbuf[wid][16 * s + 8 * half];
                            *reinterpret_cast<float4*>(dst) =
                                make_float4(r[s][0], r[s][1], r[s][2], r[s][3]);
                            *reinterpret_cast<float4*>(dst + 4) =
                                make_float4(r[s][4], r[s][5], r[s][6], r[s][7]);
                        }
                    }
                    asm volatile("s_waitcnt lgkmcnt(0)" ::: "memory");

                    // xs: np_sum_sq_128 wave-parallel, bit-exact.
                    // lane computes chain j = lane&7 (acc_j = sum of elems
                    // j, j+8, ..., j+120, ascending, mul+add no-FMA), then
                    // all lanes rebuild the exact combine tree via shfl.
                    float xs;
                    {
                        const int j = lane & 7;
                        float acc = 0.f;
                        {
#pragma clang fp contract(off)
                            for (int tt = 0; tt < 16; ++tt) {
                                float v = s_rbuf[wid][8 * tt + j];
                                acc = acc + v * v;
                            }
                        }
                        float p0 = __shfl(acc, 0), p1 = __shfl(acc, 1);
                        float p2 = __shfl(acc, 2), p3 = __shfl(acc, 3);
                        float p4 = __shfl(acc, 4), p5 = __shfl(acc, 5);
                        float p6 = __shfl(acc, 6), p7 = __shfl(acc, 7);
                        {
#pragma clang fp contract(off)
                            xs = ((p0 + p1) + (p2 + p3)) + ((p4 + p5) + (p6 + p7));
                        }
                    }

                    const float* rb = &s_rbuf[wid][0];
                    float a0 = 0.f, a1 = 0.f, a2 = 0.f, a3 = 0.f;
#pragma unroll 8
                    for (int d = 0; d < DIM; ++d) {
                        float rv = rb[d];
                        const float* row = cbTk + (size_t)d * CB_SIZE;
                        a0 = fmaf(rv, row[0],   a0);
                        a1 = fmaf(rv, row[64],  a1);
                        a2 = fmaf(rv, row[128], a2);
                        a3 = fmaf(rv, row[192], a3);
                    }
                    float dd0, dd1, dd2, dd3;
                    {
#pragma clang fp contract(off)
                        float S0 = xs + esqk[lane];
                        float S1 = xs + esqk[lane + 64];
                        float S2 = xs + esqk[lane + 128];
                        float S3 = xs + esqk[lane + 192];
                        dd0 = S0 - 2.0f * a0;
                        dd1 = S1 - 2.0f * a1;
                        dd2 = S2 - 2.0f * a2;
                        dd3 = S3 - 2.0f * a3;
                    }
                    float bd = dd0; int bc = lane;
                    if (dd1 < bd) { bd = dd1; bc = lane + 64; }
                    if (dd2 < bd) { bd = dd2; bc = lane + 128; }
                    if (dd3 < bd) { bd = dd3; bc = lane + 192; }
#pragma unroll
                    for (int d = 1; d < 64; d <<= 1) {
                        float od = __shfl_xor(bd, d);
                        int   oc = __shfl_xor(bc, d);
                        if (od < bd || (od == bd && oc < bc)) { bd = od; bc = oc; }
                    }
                    if (tk == srct) cmin = bc;
                }

                if (lane < 32)
                    out_idx[(size_t)(tokw + lane) * NUM_CB + k] = (float)cmin;

                // residual update + loss (lane's 64 dims)
                const float* ep = cbk + (size_t)cmin * DIM + 8 * half;
                float l0 = 0.f, l1 = 0.f, l2 = 0.f, l3 = 0.f;
#pragma unroll
                for (int s = 0; s < 8; ++s) {
                    float4 ev0 = *reinterpret_cast<const float4*>(ep + 16 * s);
                    float4 ev1 = *reinterpret_cast<const float4*>(ep + 16 * s + 4);
                    float d0 = ev0.x - r[s][0], d1 = ev0.y - r[s][1];
                    float d2 = ev0.z - r[s][2], d3 = ev0.w - r[s][3];
                    float d4 = ev1.x - r[s][4], d5 = ev1.y - r[s][5];
                    float d6 = ev1.z - r[s][6], d7 = ev1.w - r[s][7];
                    l0 = fmaf(d0, d0, l0); l1 = fmaf(d1, d1, l1);
                    l2 = fmaf(d2, d2, l2); l3 = fmaf(d3, d3, l3);
                    l0 = fmaf(d4, d4, l0); l1 = fmaf(d5, d5, l1);
                    l2 = fmaf(d6, d6, l2); l3 = fmaf(d7, d7, l3);
                    r[s][0] -= ev0.x; r[s][1] -= ev0.y; r[s][2] -= ev0.z; r[s][3] -= ev0.w;
                    r[s][4] -= ev1.x; r[s][5] -= ev1.y; r[s][6] -= ev1.z; r[s][7] -= ev1.w;
                }
                lsum += (double)((l0 + l1) + (l2 + l3));

                if (k < NUM_CB - 1) {   // fast re-split for next codebook
#pragma unroll
                    for (int s = 0; s < 8; ++s)
#pragma unroll
                        for (int i = 0; i < 8; ++i) {
                            unsigned short h = f2bf(r[s][i]);
                            rh[s][i] = (short)h;
                            rm[s][i] = (short)f2bf(r[s][i] - bf16_tof(h));
                        }
                }
                // ============== end epilogue ===============================
            }

            asm volatile("s_waitcnt vmcnt(0)" ::: "memory");  // prefetch landed
            __syncthreads();                                  // buf[nb] free
        }
    }

    // ---- quantized = z - r_final (lane's 64 dims) ----
    {
        const float* zp = z + (size_t)tok * DIM + 8 * half;
        float* op = out_q + (size_t)tok * DIM + 8 * half;
#pragma unroll
        for (int s = 0; s < 8; ++s) {
            float4 a = *reinterpret_cast<const float4*>(zp + 16 * s);
            float4 b = *reinterpret_cast<const float4*>(zp + 16 * s + 4);
            *reinterpret_cast<float4*>(op + 16 * s) =
                make_float4(a.x - r[s][0], a.y - r[s][1],
                            a.z - r[s][2], a.w - r[s][3]);
            *reinterpret_cast<float4*>(op + 16 * s + 4) =
                make_float4(b.x - r[s][4], b.y - r[s][5],
                            b.z - r[s][6], b.w - r[s][7]);
        }
    }

    // ---- loss reduction ----
    for (int off = 32; off > 0; off >>= 1)
        lsum += __shfl_down(lsum, off, 64);
    if (lane == 0) s_wsum[wid] = lsum;
    __syncthreads();
    if (tid == 0) {
        double tt = 0.0;
#pragma unroll
        for (int w = 0; w < 4; ++w) tt += s_wsum[w];
        atomicAdd(loss_acc, tt);
    }
}

__global__ void rvq_finalize_kernel(const double* __restrict__ loss_acc,
                                    float* __restrict__ out_loss) {
    out_loss[0] = (float)(1.25 * loss_acc[0] / (double)Q_ELEMS);
}

extern "C" void kernel_launch(void* const* d_in, const int* in_sizes, int n_in,
                              void* d_out, int out_size, void* d_ws, size_t ws_size,
                              hipStream_t stream) {
    const float* z  = (const float*)d_in[0];
    const float* cb = (const float*)d_in[1];

    float* out_q    = (float*)d_out;
    float* out_idx  = out_q + Q_ELEMS;
    float* out_loss = out_idx + I_ELEMS;

    double* loss_acc = (double*)d_ws;
    float*  esq      = (float*)((char*)d_ws + 256);               // 8 KB
    float*  esq_pk   = (float*)((char*)d_ws + 16384);             // 256 KB
    bf16x8* g_img    = (bf16x8*)((char*)d_ws + 294912);           // 1 MB
    float*  cbT      = (float*)((char*)d_ws + 294912 + 1048576);  // 1 MB

    hipMemsetAsync(loss_acc, 0, sizeof(double), stream);
    rvq_esq_kernel<<<(NUM_CB * CB_SIZE + 255) / 256, 256, 0, stream>>>(cb, esq);
    rvq_esqpk_kernel<<<(NUM_CB * 8 * 64 * 16 + 255) / 256, 256, 0, stream>>>(
        esq, esq_pk);
    rvq_split_kernel<<<(NUM_CB * CB_SIZE * 16 + 255) / 256, 256, 0, stream>>>(
        cb, g_img);
    rvq_transpose_kernel<<<(NUM_CB * DIM * CB_SIZE + 255) / 256, 256, 0,
                           stream>>>(cb, cbT);
    rvq_mfma_kernel<<<BT / 128, 256, 0, stream>>>(z, cb, cbT, esq, esq_pk,
                                                  g_img, out_q, out_idx,
                                                  loss_acc);
    rvq_finalize_kernel<<<1, 1, 0, stream>>>(loss_acc, out_loss);
}

// Round 19
// 918.327 us; speedup vs baseline: 4.9403x; 1.1041x over previous
//
#include <hip/hip_runtime.h>
#include <hip/hip_bf16.h>
#include <math.h>
#include <float.h>

#define NUM_CB 8
#define CB_SIZE 256
#define DIM 128
#define BT (16 * 16384)                  // 262144 tokens
#define Q_ELEMS ((size_t)BT * DIM)       // 33554432
#define I_ELEMS ((size_t)BT * NUM_CB)    // 2097152

#define TC 64                            // candidates per streamed tile
#define TILES_PER_CB (CB_SIZE / TC)      // 4
#define TILE_BYTES 32768                 // 2 planes x 64 cand x 16 slots x 16B

// Pass-A ambiguity margin (validated rounds 6-14). Do not shrink.
#define MARGIN_A 1.5e-4f

typedef short  bf16x8 __attribute__((ext_vector_type(8)));
typedef float  f32x4  __attribute__((ext_vector_type(4)));

__device__ __forceinline__ unsigned short bf16_rne(float f) {
    unsigned int u = __float_as_uint(f);
    u = u + 0x7FFFu + ((u >> 16) & 1u);
    return (unsigned short)(u >> 16);
}
__device__ __forceinline__ float bf16_tof(unsigned short h) {
    return __uint_as_float(((unsigned int)h) << 16);
}
__device__ __forceinline__ unsigned short f2bf(float f) {
    __hip_bfloat16 h = __float2bfloat16(f);
    return *reinterpret_cast<unsigned short*>(&h);
}

// ---------------------------------------------------------------------------
// VALIDATED np emulation (rounds 6-18): pairwise-8 sum-of-squares, no FMA.
// ---------------------------------------------------------------------------
__device__ __forceinline__ float np_sum_sq_128(const float* a) {
#pragma clang fp contract(off)
    float r0 = 0.f, r1 = 0.f, r2 = 0.f, r3 = 0.f,
          r4 = 0.f, r5 = 0.f, r6 = 0.f, r7 = 0.f;
#pragma unroll
    for (int i = 0; i < DIM; i += 8) {
        r0 = r0 + a[i + 0] * a[i + 0];
        r1 = r1 + a[i + 1] * a[i + 1];
        r2 = r2 + a[i + 2] * a[i + 2];
        r3 = r3 + a[i + 3] * a[i + 3];
        r4 = r4 + a[i + 4] * a[i + 4];
        r5 = r5 + a[i + 5] * a[i + 5];
        r6 = r6 + a[i + 6] * a[i + 6];
        r7 = r7 + a[i + 7] * a[i + 7];
    }
    return ((r0 + r1) + (r2 + r3)) + ((r4 + r5) + (r6 + r7));
}

__global__ void rvq_esq_kernel(const float* __restrict__ cb,
                               float* __restrict__ esq) {
    int i = blockIdx.x * blockDim.x + threadIdx.x;   // 0 .. 2047
    if (i >= NUM_CB * CB_SIZE) return;
    esq[i] = np_sum_sq_128(cb + (size_t)i * DIM);
}

// Transposed f32 codebook for coalesced Pass-B reads: cbT[k][d][c]
__global__ void rvq_transpose_kernel(const float* __restrict__ cb,
                                     float* __restrict__ cbT) {
    int idx = blockIdx.x * blockDim.x + threadIdx.x;   // 0 .. 262143
    if (idx >= NUM_CB * DIM * CB_SIZE) return;
    int c = idx & (CB_SIZE - 1);
    int d = (idx >> 8) & (DIM - 1);
    int k = idx >> 15;
    cbT[idx] = cb[((size_t)(k * CB_SIZE + c)) * DIM + d];
}

// ---------------------------------------------------------------------------
// Precompute merged bf16 hi|lo image in the swizzled LDS layout (validated):
// img[t*2048 + plane*1024 + cand*16 + (slot ^ (cand&15))], t = k*4 + T,
// codeword = t*64 + cand.
// ---------------------------------------------------------------------------
__global__ void rvq_split_kernel(const float* __restrict__ cb,
                                 bf16x8* __restrict__ g_img) {
    int idx = blockIdx.x * blockDim.x + threadIdx.x;   // 0 .. 32767
    if (idx >= NUM_CB * CB_SIZE * 16) return;
    int slot = idx & 15;
    int cand = (idx >> 4) & (TC - 1);
    int t    = idx >> 10;                 // 0..31
    const float* src = cb + ((size_t)t * TC + cand) * DIM + slot * 8;
    float4 a = *reinterpret_cast<const float4*>(src);
    float4 b = *reinterpret_cast<const float4*>(src + 4);
    float e[8] = {a.x, a.y, a.z, a.w, b.x, b.y, b.z, b.w};
    bf16x8 eh, el;
#pragma unroll
    for (int i = 0; i < 8; ++i) {
        unsigned short h = bf16_rne(e[i]);
        float rem = e[i] - bf16_tof(h);
        eh[i] = (short)h;
        el[i] = (short)bf16_rne(rem);
    }
    int ds = slot ^ (cand & 15);
    g_img[(size_t)t * 2048 + cand * 16 + ds]        = eh;
    g_img[(size_t)t * 2048 + 1024 + cand * 16 + ds] = el;
}

// DMA one 32KB tile into LDS buffer: 4 x global_load_lds(16B) per wave (8 wv).
__device__ __forceinline__ void stage_tile(const bf16x8* __restrict__ g_img,
                                           bf16x8 (*s_buf)[2048],
                                           int t, int nb, int wid, int lane) {
    const char* gt = (const char*)g_img + (size_t)t * TILE_BYTES
                     + wid * 4096 + lane * 16;
    const char* lb = (const char*)(&s_buf[nb][0]) + wid * 4096;  // wave-uniform
#pragma unroll
    for (int c = 0; c < 4; ++c) {
        __builtin_amdgcn_global_load_lds(
            (const __attribute__((address_space(1))) unsigned int*)(gt + c * 1024),
            (__attribute__((address_space(3))) unsigned int*)(lb + c * 1024),
            16, 0, 0);
    }
}

// ---------------------------------------------------------------------------
// Main fused kernel: 128 tokens/block (8 waves x 16), residual in VGPRs.
// SWAPPED MFMA: mfma(E, R) -> lane holds its OWN token's candidate scores
// (D col = token = lane&15, D row = candidate = 4*lq + j). Per-lane top-2,
// 2-step cross-lq reduce, no LDS selection traffic.
// __launch_bounds__(512, 2): 128-VGPR cap -- NO SPILL (proven round 14:
// VGPR=128, hbm ~0.4GB, 918 us). (512,4) clamps to 64 VGPR and spills.
// ---------------------------------------------------------------------------
__global__ __launch_bounds__(512, 2) void rvq_mfma_kernel(
    const float* __restrict__ z,
    const float* __restrict__ cb,
    const float* __restrict__ cbT,
    const float* __restrict__ esq,
    const bf16x8* __restrict__ g_img,
    float* __restrict__ out_q,
    float* __restrict__ out_idx,
    double* __restrict__ loss_acc) {

    __shared__ bf16x8 s_buf[2][2048];                // 2 x 32KB double buffer
    __shared__ __align__(16) float s_rbuf[8][DIM];   // per-wave passB residual
    __shared__ double s_wsum[8];

    const int tid  = threadIdx.x;
    const int wid  = tid >> 6;
    const int lane = tid & 63;
    const int lrow = lane & 15;       // token-in-wave (B col / D col)
    const int lq   = lane >> 4;       // k-chunk group / D row group
    const int tokw = blockIdx.x * 128 + wid * 16;
    const int tok  = tokw + lrow;

    // ---- residual chunks: r[s][i] = z[tok][32s + 8lq + i] ----
    float r[4][8];
    {
        const float* zp = z + (size_t)tok * DIM + 8 * lq;
#pragma unroll
        for (int s = 0; s < 4; ++s) {
            float4 a = *reinterpret_cast<const float4*>(zp + 32 * s);
            float4 b = *reinterpret_cast<const float4*>(zp + 32 * s + 4);
            r[s][0] = a.x; r[s][1] = a.y; r[s][2] = a.z; r[s][3] = a.w;
            r[s][4] = b.x; r[s][5] = b.y; r[s][6] = b.z; r[s][7] = b.w;
        }
    }

    // ---- fast bf16 hi/mid split (HW RNE casts) ----
    bf16x8 ah[4], am[4];
#pragma unroll
    for (int s = 0; s < 4; ++s)
#pragma unroll
        for (int i = 0; i < 8; ++i) {
            unsigned short h = f2bf(r[s][i]);
            float rem = r[s][i] - bf16_tof(h);
            ah[s][i] = (short)h;
            am[s][i] = (short)f2bf(rem);
        }

    double lsum = 0.0;

    // prologue: stage tile 0
    stage_tile(g_img, s_buf, 0, 0, wid, lane);
    asm volatile("s_waitcnt vmcnt(0)" ::: "memory");
    __syncthreads();

    for (int k = 0; k < NUM_CB; ++k) {
        const float* esqk = esq + k * CB_SIZE;
        const float* cbk  = cb  + (size_t)k * CB_SIZE * DIM;
        const float* cbTk = cbT + (size_t)k * DIM * CB_SIZE + lane;

        float m1 = FLT_MAX, m2 = FLT_MAX;
        int   i1 = 0x7fffffff;

#pragma unroll
        for (int T = 0; T < TILES_PER_CB; ++T) {
            const int t  = k * TILES_PER_CB + T;
            const int nb = T & 1;
            if (k < NUM_CB - 1 || T < TILES_PER_CB - 1)
                stage_tile(g_img, s_buf, t + 1, nb ^ 1, wid, lane);

#pragma unroll
            for (int ctl = 0; ctl < 4; ++ctl) {   // 16-candidate column tiles
                const int ctg  = T * 4 + ctl;     // global ct 0..15
                const int base = (ctl * 16 + lrow) * 16;
                bf16x8 bh[4], bl[4];
#pragma unroll
                for (int s = 0; s < 4; ++s) {
                    int ls = (4 * s + lq) ^ lrow;
                    bh[s] = s_buf[nb][base + ls];
                    bl[s] = s_buf[nb][1024 + base + ls];
                }
                f32x4 acc0 = {0.f, 0.f, 0.f, 0.f};
                f32x4 acc1 = {0.f, 0.f, 0.f, 0.f};
                // SWAPPED: A = codebook frag, B = residual frag
                acc0 = __builtin_amdgcn_mfma_f32_16x16x32_bf16(bh[0], ah[0], acc0, 0, 0, 0);
                acc0 = __builtin_amdgcn_mfma_f32_16x16x32_bf16(bh[1], ah[1], acc0, 0, 0, 0);
                acc1 = __builtin_amdgcn_mfma_f32_16x16x32_bf16(bh[2], ah[2], acc1, 0, 0, 0);
                acc1 = __builtin_amdgcn_mfma_f32_16x16x32_bf16(bh[3], ah[3], acc1, 0, 0, 0);
                acc0 = __builtin_amdgcn_mfma_f32_16x16x32_bf16(bh[0], am[0], acc0, 0, 0, 0);
                acc0 = __builtin_amdgcn_mfma_f32_16x16x32_bf16(bh[1], am[1], acc0, 0, 0, 0);
                acc1 = __builtin_amdgcn_mfma_f32_16x16x32_bf16(bh[2], am[2], acc1, 0, 0, 0);
                acc1 = __builtin_amdgcn_mfma_f32_16x16x32_bf16(bh[3], am[3], acc1, 0, 0, 0);
                acc0 = __builtin_amdgcn_mfma_f32_16x16x32_bf16(bl[0], ah[0], acc0, 0, 0, 0);
                acc0 = __builtin_amdgcn_mfma_f32_16x16x32_bf16(bl[1], ah[1], acc0, 0, 0, 0);
                acc1 = __builtin_amdgcn_mfma_f32_16x16x32_bf16(bl[2], ah[2], acc1, 0, 0, 0);
                acc1 = __builtin_amdgcn_mfma_f32_16x16x32_bf16(bl[3], ah[3], acc1, 0, 0, 0);

                // scores: candidate c = ctg*16 + 4*lq + j for THIS lane's token
                float4 ev = *reinterpret_cast<const float4*>(
                    esqk + ctg * 16 + 4 * lq);
                const float es[4] = {ev.x, ev.y, ev.z, ev.w};
                const int cb0 = ctg * 16 + 4 * lq;
#pragma unroll
                for (int j = 0; j < 4; ++j) {
                    float s = fmaf(-2.0f, acc0[j] + acc1[j], es[j]);
                    m2 = fminf(m2, fmaxf(m1, s));
                    if (s < m1) { m1 = s; i1 = cb0 + j; }   // ascending c order
                }
            }

            if (T == TILES_PER_CB - 1) {
                // ============== per-codebook epilogue (wave-internal) ======
                // cross-lq top-2 lexicographic reduce (2 butterfly steps)
#pragma unroll
                for (int d = 16; d < 64; d <<= 1) {
                    float om1 = __shfl_xor(m1, d);
                    float om2 = __shfl_xor(m2, d);
                    int   oi1 = __shfl_xor(i1, d);
                    bool ow = (om1 < m1) || (om1 == m1 && oi1 < i1);
                    float lo = ow ? m1 : om1;
                    m1 = ow ? om1 : m1;
                    i1 = ow ? oi1 : i1;
                    m2 = fminf(fminf(m2, om2), lo);
                }
                int cmin = i1;

                // Pass B (rare): exact np argmin, coalesced cbT (validated)
                bool amb = !(m2 - m1 > MARGIN_A);
                unsigned long long mask = __ballot(amb && lane < 16);
                while (mask) {
                    int srct = __ffsll(mask) - 1;
                    mask &= mask - 1;
                    if (lrow == srct) {
#pragma unroll
                        for (int s = 0; s < 4; ++s) {
                            float4* dst = reinterpret_cast<float4*>(
                                &s_rbuf[wid][32 * s + 8 * lq]);
                            dst[0] = make_float4(r[s][0], r[s][1], r[s][2], r[s][3]);
                            dst[1] = make_float4(r[s][4], r[s][5], r[s][6], r[s][7]);
                        }
                    }
                    asm volatile("s_waitcnt lgkmcnt(0)" ::: "memory");
                    float xs = 0.f;
                    if (lane == 0) xs = np_sum_sq_128(&s_rbuf[wid][0]);
                    xs = __shfl(xs, 0);

                    const float* rb = &s_rbuf[wid][0];
                    float a0 = 0.f, a1 = 0.f, a2 = 0.f, a3 = 0.f;
#pragma unroll 8
                    for (int d = 0; d < DIM; ++d) {
                        float rv = rb[d];
                        const float* row = cbTk + (size_t)d * CB_SIZE;
                        a0 = fmaf(rv, row[0],   a0);
                        a1 = fmaf(rv, row[64],  a1);
                        a2 = fmaf(rv, row[128], a2);
                        a3 = fmaf(rv, row[192], a3);
                    }
                    float dd0, dd1, dd2, dd3;
                    {
#pragma clang fp contract(off)
                        float S0 = xs + esqk[lane];
                        float S1 = xs + esqk[lane + 64];
                        float S2 = xs + esqk[lane + 128];
                        float S3 = xs + esqk[lane + 192];
                        dd0 = S0 - 2.0f * a0;
                        dd1 = S1 - 2.0f * a1;
                        dd2 = S2 - 2.0f * a2;
                        dd3 = S3 - 2.0f * a3;
                    }
                    float bd = dd0; int bc = lane;
                    if (dd1 < bd) { bd = dd1; bc = lane + 64; }
                    if (dd2 < bd) { bd = dd2; bc = lane + 128; }
                    if (dd3 < bd) { bd = dd3; bc = lane + 192; }
#pragma unroll
                    for (int d = 1; d < 64; d <<= 1) {
                        float od = __shfl_xor(bd, d);
                        int   oc = __shfl_xor(bc, d);
                        if (od < bd || (od == bd && oc < bc)) { bd = od; bc = oc; }
                    }
                    if (lrow == srct) cmin = bc;   // all lanes have (bd,bc)
                }

                if (lane < 16)    // lane==lrow owner copy
                    out_idx[(size_t)(tokw + lane) * NUM_CB + k] = (float)cmin;

                // residual update + loss
                const float* ep = cbk + (size_t)cmin * DIM + 8 * lq;
                float l0 = 0.f, l1 = 0.f, l2 = 0.f, l3 = 0.f;
#pragma unroll
                for (int s = 0; s < 4; ++s) {
                    float4 ev0 = *reinterpret_cast<const float4*>(ep + 32 * s);
                    float4 ev1 = *reinterpret_cast<const float4*>(ep + 32 * s + 4);
                    float d0 = ev0.x - r[s][0], d1 = ev0.y - r[s][1];
                    float d2 = ev0.z - r[s][2], d3 = ev0.w - r[s][3];
                    float d4 = ev1.x - r[s][4], d5 = ev1.y - r[s][5];
                    float d6 = ev1.z - r[s][6], d7 = ev1.w - r[s][7];
                    l0 = fmaf(d0, d0, l0); l1 = fmaf(d1, d1, l1);
                    l2 = fmaf(d2, d2, l2); l3 = fmaf(d3, d3, l3);
                    l0 = fmaf(d4, d4, l0); l1 = fmaf(d5, d5, l1);
                    l2 = fmaf(d6, d6, l2); l3 = fmaf(d7, d7, l3);
                    r[s][0] -= ev0.x; r[s][1] -= ev0.y; r[s][2] -= ev0.z; r[s][3] -= ev0.w;
                    r[s][4] -= ev1.x; r[s][5] -= ev1.y; r[s][6] -= ev1.z; r[s][7] -= ev1.w;
                }
                lsum += (double)((l0 + l1) + (l2 + l3));

                if (k < NUM_CB - 1) {   // fast re-split for next codebook
#pragma unroll
                    for (int s = 0; s < 4; ++s)
#pragma unroll
                        for (int i = 0; i < 8; ++i) {
                            unsigned short h = f2bf(r[s][i]);
                            float rem = r[s][i] - bf16_tof(h);
                            ah[s][i] = (short)h;
                            am[s][i] = (short)f2bf(rem);
                        }
                }
                // ============== end epilogue ===============================
            }

            asm volatile("s_waitcnt vmcnt(0)" ::: "memory");  // prefetch landed
            __syncthreads();                                  // buf[nb] free
        }
    }

    // ---- quantized = z - r_final ----
    {
        const float* zp = z + (size_t)tok * DIM + 8 * lq;
        float* op = out_q + (size_t)tok * DIM + 8 * lq;
#pragma unroll
        for (int s = 0; s < 4; ++s) {
            float4 a = *reinterpret_cast<const float4*>(zp + 32 * s);
            float4 b = *reinterpret_cast<const float4*>(zp + 32 * s + 4);
            *reinterpret_cast<float4*>(op + 32 * s) =
                make_float4(a.x - r[s][0], a.y - r[s][1],
                            a.z - r[s][2], a.w - r[s][3]);
            *reinterpret_cast<float4*>(op + 32 * s + 4) =
                make_float4(b.x - r[s][4], b.y - r[s][5],
                            b.z - r[s][6], b.w - r[s][7]);
        }
    }

    // ---- loss reduction ----
    for (int off = 32; off > 0; off >>= 1)
        lsum += __shfl_down(lsum, off, 64);
    if (lane == 0) s_wsum[wid] = lsum;
    __syncthreads();
    if (tid == 0) {
        double t = 0.0;
#pragma unroll
        for (int w = 0; w < 8; ++w) t += s_wsum[w];
        atomicAdd(loss_acc, t);
    }
}

__global__ void rvq_finalize_kernel(const double* __restrict__ loss_acc,
                                    float* __restrict__ out_loss) {
    out_loss[0] = (float)(1.25 * loss_acc[0] / (double)Q_ELEMS);
}

extern "C" void kernel_launch(void* const* d_in, const int* in_sizes, int n_in,
                              void* d_out, int out_size, void* d_ws, size_t ws_size,
                              hipStream_t stream) {
    const float* z  = (const float*)d_in[0];
    const float* cb = (const float*)d_in[1];

    float* out_q    = (float*)d_out;
    float* out_idx  = out_q + Q_ELEMS;
    float* out_loss = out_idx + I_ELEMS;

    double* loss_acc = (double*)d_ws;
    float*  esq      = (float*)((char*)d_ws + 256);              // 8 KB
    bf16x8* g_img    = (bf16x8*)((char*)d_ws + 65536);           // 1 MB
    float*  cbT      = (float*)((char*)d_ws + 65536 + 1048576);  // 1 MB

    hipMemsetAsync(loss_acc, 0, sizeof(double), stream);
    rvq_esq_kernel<<<(NUM_CB * CB_SIZE + 255) / 256, 256, 0, stream>>>(cb, esq);
    rvq_split_kernel<<<(NUM_CB * CB_SIZE * 16 + 255) / 256, 256, 0, stream>>>(
        cb, g_img);
    rvq_transpose_kernel<<<(NUM_CB * DIM * CB_SIZE + 255) / 256, 256, 0,
                           stream>>>(cb, cbT);
    rvq_mfma_kernel<<<BT / 128, 512, 0, stream>>>(z, cb, cbT, esq, g_img,
                                                  out_q, out_idx, loss_acc);
    rvq_finalize_kernel<<<1, 1, 0, stream>>>(loss_acc, out_loss);
}

// Round 20
// 901.813 us; speedup vs baseline: 5.0307x; 1.0183x over previous
//
#include <hip/hip_runtime.h>
#include <hip/hip_bf16.h>
#include <math.h>
#include <float.h>

#define NUM_CB 8
#define CB_SIZE 256
#define DIM 128
#define BT (16 * 16384)                  // 262144 tokens
#define Q_ELEMS ((size_t)BT * DIM)       // 33554432
#define I_ELEMS ((size_t)BT * NUM_CB)    // 2097152

// Pass-A ambiguity margin (validated rounds 6-19). Do not shrink.
#define MARGIN_A 1.5e-4f

typedef short  bf16x8 __attribute__((ext_vector_type(8)));
typedef float  f32x4  __attribute__((ext_vector_type(4)));

__device__ __forceinline__ unsigned short bf16_rne(float f) {
    unsigned int u = __float_as_uint(f);
    u = u + 0x7FFFu + ((u >> 16) & 1u);
    return (unsigned short)(u >> 16);
}
__device__ __forceinline__ float bf16_tof(unsigned short h) {
    return __uint_as_float(((unsigned int)h) << 16);
}
__device__ __forceinline__ unsigned short f2bf(float f) {
    __hip_bfloat16 h = __float2bfloat16(f);
    return *reinterpret_cast<unsigned short*>(&h);
}

// ---------------------------------------------------------------------------
// VALIDATED np emulation (rounds 6-19): pairwise-8 sum-of-squares, no FMA.
// ---------------------------------------------------------------------------
__device__ __forceinline__ float np_sum_sq_128(const float* a) {
#pragma clang fp contract(off)
    float r0 = 0.f, r1 = 0.f, r2 = 0.f, r3 = 0.f,
          r4 = 0.f, r5 = 0.f, r6 = 0.f, r7 = 0.f;
#pragma unroll
    for (int i = 0; i < DIM; i += 8) {
        r0 = r0 + a[i + 0] * a[i + 0];
        r1 = r1 + a[i + 1] * a[i + 1];
        r2 = r2 + a[i + 2] * a[i + 2];
        r3 = r3 + a[i + 3] * a[i + 3];
        r4 = r4 + a[i + 4] * a[i + 4];
        r5 = r5 + a[i + 5] * a[i + 5];
        r6 = r6 + a[i + 6] * a[i + 6];
        r7 = r7 + a[i + 7] * a[i + 7];
    }
    return ((r0 + r1) + (r2 + r3)) + ((r4 + r5) + (r6 + r7));
}

__global__ void rvq_esq_kernel(const float* __restrict__ cb,
                               float* __restrict__ esq) {
    int i = blockIdx.x * blockDim.x + threadIdx.x;   // 0 .. 2047
    if (i >= NUM_CB * CB_SIZE) return;
    esq[i] = np_sum_sq_128(cb + (size_t)i * DIM);
}

// Transposed f32 codebook for coalesced Pass-B reads: cbT[k][d][c]
__global__ void rvq_transpose_kernel(const float* __restrict__ cb,
                                     float* __restrict__ cbT) {
    int idx = blockIdx.x * blockDim.x + threadIdx.x;   // 0 .. 262143
    if (idx >= NUM_CB * DIM * CB_SIZE) return;
    int c = idx & (CB_SIZE - 1);
    int d = (idx >> 8) & (DIM - 1);
    int k = idx >> 15;
    cbT[idx] = cb[((size_t)(k * CB_SIZE + c)) * DIM + d];
}

// ---------------------------------------------------------------------------
// Precompute bf16 hi|lo fragment image in WAVE-COALESCED GLOBAL layout:
// g2[(((k*16 + ctg)*2 + plane)*4 + s)*64 + lane] = plane(hi/lo) bf16x8 of
//   candidate c = ctg*16 + (lane&15), dims 8*(4*s + (lane>>4)) .. +8.
// Each fragment fetch in the main loop is then one contiguous 1KB
// global_load_dwordx4 across the wave (lane*16B), L2-resident (1 MB total).
// Fragment values are bit-identical to the r19 LDS-staged path.
// ---------------------------------------------------------------------------
__global__ void rvq_split2_kernel(const float* __restrict__ cb,
                                  bf16x8* __restrict__ g2) {
    int idx = blockIdx.x * blockDim.x + threadIdx.x;   // 0 .. 65535
    if (idx >= NUM_CB * 16 * 2 * 4 * 64) return;
    int lane  = idx & 63;
    int s     = (idx >> 6) & 3;
    int plane = (idx >> 8) & 1;
    int ctg   = (idx >> 9) & 15;
    int k     = idx >> 13;
    int cand  = ctg * 16 + (lane & 15);
    int slot  = 4 * s + (lane >> 4);
    const float* src = cb + ((size_t)(k * CB_SIZE + cand)) * DIM + slot * 8;
    float4 a = *reinterpret_cast<const float4*>(src);
    float4 b = *reinterpret_cast<const float4*>(src + 4);
    float e[8] = {a.x, a.y, a.z, a.w, b.x, b.y, b.z, b.w};
    bf16x8 v;
#pragma unroll
    for (int i = 0; i < 8; ++i) {
        unsigned short h = bf16_rne(e[i]);
        if (plane == 0) {
            v[i] = (short)h;
        } else {
            float rem = e[i] - bf16_tof(h);
            v[i] = (short)bf16_rne(rem);
        }
    }
    g2[idx] = v;
}

// ---------------------------------------------------------------------------
// Main fused kernel: 128 tokens/block (8 waves x 16), residual in VGPRs.
// SWAPPED MFMA (A = codebook frag, B = residual frag), fragments read
// DIRECTLY from the L2-resident g2 image (coalesced 1KB loads) -- NO LDS
// staging, NO barriers in the main loop: waves free-run, VMEM latency
// hidden by 4 waves/SIMD + 8-deep load clauses.
// __launch_bounds__(512, 2): 128-VGPR cap (r14/r19-proven no-spill budget).
// ---------------------------------------------------------------------------
__global__ __launch_bounds__(512, 2) void rvq_mfma_kernel(
    const float* __restrict__ z,
    const float* __restrict__ cb,
    const float* __restrict__ cbT,
    const float* __restrict__ esq,
    const bf16x8* __restrict__ g2,
    float* __restrict__ out_q,
    float* __restrict__ out_idx,
    double* __restrict__ loss_acc) {

    __shared__ __align__(16) float s_rbuf[8][DIM];   // per-wave passB residual
    __shared__ double s_wsum[8];

    const int tid  = threadIdx.x;
    const int wid  = tid >> 6;
    const int lane = tid & 63;
    const int lrow = lane & 15;       // token-in-wave (B col / D col)
    const int lq   = lane >> 4;       // k-chunk group / D row group
    const int tokw = blockIdx.x * 128 + wid * 16;
    const int tok  = tokw + lrow;

    // ---- residual chunks: r[s][i] = z[tok][32s + 8lq + i] ----
    float r[4][8];
    {
        const float* zp = z + (size_t)tok * DIM + 8 * lq;
#pragma unroll
        for (int s = 0; s < 4; ++s) {
            float4 a = *reinterpret_cast<const float4*>(zp + 32 * s);
            float4 b = *reinterpret_cast<const float4*>(zp + 32 * s + 4);
            r[s][0] = a.x; r[s][1] = a.y; r[s][2] = a.z; r[s][3] = a.w;
            r[s][4] = b.x; r[s][5] = b.y; r[s][6] = b.z; r[s][7] = b.w;
        }
    }

    // ---- fast bf16 hi/mid split (HW RNE casts) ----
    bf16x8 ah[4], am[4];
#pragma unroll
    for (int s = 0; s < 4; ++s)
#pragma unroll
        for (int i = 0; i < 8; ++i) {
            unsigned short h = f2bf(r[s][i]);
            float rem = r[s][i] - bf16_tof(h);
            ah[s][i] = (short)h;
            am[s][i] = (short)f2bf(rem);
        }

    double lsum = 0.0;

    for (int k = 0; k < NUM_CB; ++k) {
        const float* esqk = esq + k * CB_SIZE;
        const float* cbk  = cb  + (size_t)k * CB_SIZE * DIM;
        const float* cbTk = cbT + (size_t)k * DIM * CB_SIZE + lane;

        float m1 = FLT_MAX, m2 = FLT_MAX;
        int   i1 = 0x7fffffff;

#pragma unroll 4
        for (int ctg = 0; ctg < 16; ++ctg) {   // 16-candidate column tiles
            // fragments: 8 coalesced 1KB loads from the L2-resident image
            const bf16x8* gp = g2 + ((size_t)(k * 16 + ctg) * 8 * 64) + lane;
            bf16x8 bh[4], bl[4];
#pragma unroll
            for (int s = 0; s < 4; ++s) {
                bh[s] = gp[s * 64];
                bl[s] = gp[(4 + s) * 64];
            }
            f32x4 acc0 = {0.f, 0.f, 0.f, 0.f};
            f32x4 acc1 = {0.f, 0.f, 0.f, 0.f};
            // SWAPPED: A = codebook frag, B = residual frag
            acc0 = __builtin_amdgcn_mfma_f32_16x16x32_bf16(bh[0], ah[0], acc0, 0, 0, 0);
            acc0 = __builtin_amdgcn_mfma_f32_16x16x32_bf16(bh[1], ah[1], acc0, 0, 0, 0);
            acc1 = __builtin_amdgcn_mfma_f32_16x16x32_bf16(bh[2], ah[2], acc1, 0, 0, 0);
            acc1 = __builtin_amdgcn_mfma_f32_16x16x32_bf16(bh[3], ah[3], acc1, 0, 0, 0);
            acc0 = __builtin_amdgcn_mfma_f32_16x16x32_bf16(bh[0], am[0], acc0, 0, 0, 0);
            acc0 = __builtin_amdgcn_mfma_f32_16x16x32_bf16(bh[1], am[1], acc0, 0, 0, 0);
            acc1 = __builtin_amdgcn_mfma_f32_16x16x32_bf16(bh[2], am[2], acc1, 0, 0, 0);
            acc1 = __builtin_amdgcn_mfma_f32_16x16x32_bf16(bh[3], am[3], acc1, 0, 0, 0);
            acc0 = __builtin_amdgcn_mfma_f32_16x16x32_bf16(bl[0], ah[0], acc0, 0, 0, 0);
            acc0 = __builtin_amdgcn_mfma_f32_16x16x32_bf16(bl[1], ah[1], acc0, 0, 0, 0);
            acc1 = __builtin_amdgcn_mfma_f32_16x16x32_bf16(bl[2], ah[2], acc1, 0, 0, 0);
            acc1 = __builtin_amdgcn_mfma_f32_16x16x32_bf16(bl[3], ah[3], acc1, 0, 0, 0);

            // scores: candidate c = ctg*16 + 4*lq + j for THIS lane's token
            float4 ev = *reinterpret_cast<const float4*>(
                esqk + ctg * 16 + 4 * lq);
            const float es[4] = {ev.x, ev.y, ev.z, ev.w};
            const int cb0 = ctg * 16 + 4 * lq;
#pragma unroll
            for (int j = 0; j < 4; ++j) {
                float s = fmaf(-2.0f, acc0[j] + acc1[j], es[j]);
                m2 = fminf(m2, fmaxf(m1, s));
                if (s < m1) { m1 = s; i1 = cb0 + j; }   // ascending c order
            }
        }

        // ============== per-codebook epilogue (wave-internal) ==============
        // cross-lq top-2 lexicographic reduce (2 butterfly steps)
#pragma unroll
        for (int d = 16; d < 64; d <<= 1) {
            float om1 = __shfl_xor(m1, d);
            float om2 = __shfl_xor(m2, d);
            int   oi1 = __shfl_xor(i1, d);
            bool ow = (om1 < m1) || (om1 == m1 && oi1 < i1);
            float lo = ow ? m1 : om1;
            m1 = ow ? om1 : m1;
            i1 = ow ? oi1 : i1;
            m2 = fminf(fminf(m2, om2), lo);
        }
        int cmin = i1;

        // Pass B (rare): exact np argmin, coalesced cbT (validated)
        bool amb = !(m2 - m1 > MARGIN_A);
        unsigned long long mask = __ballot(amb && lane < 16);
        while (mask) {
            int srct = __ffsll(mask) - 1;
            mask &= mask - 1;
            if (lrow == srct) {
#pragma unroll
                for (int s = 0; s < 4; ++s) {
                    float4* dst = reinterpret_cast<float4*>(
                        &s_rbuf[wid][32 * s + 8 * lq]);
                    dst[0] = make_float4(r[s][0], r[s][1], r[s][2], r[s][3]);
                    dst[1] = make_float4(r[s][4], r[s][5], r[s][6], r[s][7]);
                }
            }
            asm volatile("s_waitcnt lgkmcnt(0)" ::: "memory");
            float xs = 0.f;
            if (lane == 0) xs = np_sum_sq_128(&s_rbuf[wid][0]);
            xs = __shfl(xs, 0);

            const float* rb = &s_rbuf[wid][0];
            float a0 = 0.f, a1 = 0.f, a2 = 0.f, a3 = 0.f;
#pragma unroll 8
            for (int d = 0; d < DIM; ++d) {
                float rv = rb[d];
                const float* row = cbTk + (size_t)d * CB_SIZE;
                a0 = fmaf(rv, row[0],   a0);
                a1 = fmaf(rv, row[64],  a1);
                a2 = fmaf(rv, row[128], a2);
                a3 = fmaf(rv, row[192], a3);
            }
            float dd0, dd1, dd2, dd3;
            {
#pragma clang fp contract(off)
                float S0 = xs + esqk[lane];
                float S1 = xs + esqk[lane + 64];
                float S2 = xs + esqk[lane + 128];
                float S3 = xs + esqk[lane + 192];
                dd0 = S0 - 2.0f * a0;
                dd1 = S1 - 2.0f * a1;
                dd2 = S2 - 2.0f * a2;
                dd3 = S3 - 2.0f * a3;
            }
            float bd = dd0; int bc = lane;
            if (dd1 < bd) { bd = dd1; bc = lane + 64; }
            if (dd2 < bd) { bd = dd2; bc = lane + 128; }
            if (dd3 < bd) { bd = dd3; bc = lane + 192; }
#pragma unroll
            for (int d = 1; d < 64; d <<= 1) {
                float od = __shfl_xor(bd, d);
                int   oc = __shfl_xor(bc, d);
                if (od < bd || (od == bd && oc < bc)) { bd = od; bc = oc; }
            }
            if (lrow == srct) cmin = bc;   // all lanes have (bd,bc)
        }

        if (lane < 16)    // lane==lrow owner copy
            out_idx[(size_t)(tokw + lane) * NUM_CB + k] = (float)cmin;

        // residual update + loss
        const float* ep = cbk + (size_t)cmin * DIM + 8 * lq;
        float l0 = 0.f, l1 = 0.f, l2 = 0.f, l3 = 0.f;
#pragma unroll
        for (int s = 0; s < 4; ++s) {
            float4 ev0 = *reinterpret_cast<const float4*>(ep + 32 * s);
            float4 ev1 = *reinterpret_cast<const float4*>(ep + 32 * s + 4);
            float d0 = ev0.x - r[s][0], d1 = ev0.y - r[s][1];
            float d2 = ev0.z - r[s][2], d3 = ev0.w - r[s][3];
            float d4 = ev1.x - r[s][4], d5 = ev1.y - r[s][5];
            float d6 = ev1.z - r[s][6], d7 = ev1.w - r[s][7];
            l0 = fmaf(d0, d0, l0); l1 = fmaf(d1, d1, l1);
            l2 = fmaf(d2, d2, l2); l3 = fmaf(d3, d3, l3);
            l0 = fmaf(d4, d4, l0); l1 = fmaf(d5, d5, l1);
            l2 = fmaf(d6, d6, l2); l3 = fmaf(d7, d7, l3);
            r[s][0] -= ev0.x; r[s][1] -= ev0.y; r[s][2] -= ev0.z; r[s][3] -= ev0.w;
            r[s][4] -= ev1.x; r[s][5] -= ev1.y; r[s][6] -= ev1.z; r[s][7] -= ev1.w;
        }
        lsum += (double)((l0 + l1) + (l2 + l3));

        if (k < NUM_CB - 1) {   // fast re-split for next codebook
#pragma unroll
            for (int s = 0; s < 4; ++s)
#pragma unroll
                for (int i = 0; i < 8; ++i) {
                    unsigned short h = f2bf(r[s][i]);
                    float rem = r[s][i] - bf16_tof(h);
                    ah[s][i] = (short)h;
                    am[s][i] = (short)f2bf(rem);
                }
        }
        // ============== end epilogue =======================================
    }

    // ---- quantized = z - r_final ----
    {
        const float* zp = z + (size_t)tok * DIM + 8 * lq;
        float* op = out_q + (size_t)tok * DIM + 8 * lq;
#pragma unroll
        for (int s = 0; s < 4; ++s) {
            float4 a = *reinterpret_cast<const float4*>(zp + 32 * s);
            float4 b = *reinterpret_cast<const float4*>(zp + 32 * s + 4);
            *reinterpret_cast<float4*>(op + 32 * s) =
                make_float4(a.x - r[s][0], a.y - r[s][1],
                            a.z - r[s][2], a.w - r[s][3]);
            *reinterpret_cast<float4*>(op + 32 * s + 4) =
                make_float4(b.x - r[s][4], b.y - r[s][5],
                            b.z - r[s][6], b.w - r[s][7]);
        }
    }

    // ---- loss reduction ----
    for (int off = 32; off > 0; off >>= 1)
        lsum += __shfl_down(lsum, off, 64);
    if (lane == 0) s_wsum[wid] = lsum;
    __syncthreads();
    if (tid == 0) {
        double t = 0.0;
#pragma unroll
        for (int w = 0; w < 8; ++w) t += s_wsum[w];
        atomicAdd(loss_acc, t);
    }
}

__global__ void rvq_finalize_kernel(const double* __restrict__ loss_acc,
                                    float* __restrict__ out_loss) {
    out_loss[0] = (float)(1.25 * loss_acc[0] / (double)Q_ELEMS);
}

extern "C" void kernel_launch(void* const* d_in, const int* in_sizes, int n_in,
                              void* d_out, int out_size, void* d_ws, size_t ws_size,
                              hipStream_t stream) {
    const float* z  = (const float*)d_in[0];
    const float* cb = (const float*)d_in[1];

    float* out_q    = (float*)d_out;
    float* out_idx  = out_q + Q_ELEMS;
    float* out_loss = out_idx + I_ELEMS;

    double* loss_acc = (double*)d_ws;
    float*  esq      = (float*)((char*)d_ws + 256);              // 8 KB
    bf16x8* g2       = (bf16x8*)((char*)d_ws + 65536);           // 1 MB
    float*  cbT      = (float*)((char*)d_ws + 65536 + 1048576);  // 1 MB

    hipMemsetAsync(loss_acc, 0, sizeof(double), stream);
    rvq_esq_kernel<<<(NUM_CB * CB_SIZE + 255) / 256, 256, 0, stream>>>(cb, esq);
    rvq_split2_kernel<<<(NUM_CB * 16 * 2 * 4 * 64 + 255) / 256, 256, 0,
                        stream>>>(cb, g2);
    rvq_transpose_kernel<<<(NUM_CB * DIM * CB_SIZE + 255) / 256, 256, 0,
                           stream>>>(cb, cbT);
    rvq_mfma_kernel<<<BT / 128, 512, 0, stream>>>(z, cb, cbT, esq, g2,
                                                  out_q, out_idx, loss_acc);
    rvq_finalize_kernel<<<1, 1, 0, stream>>>(loss_acc, out_loss);
}

// Round 21
// 900.175 us; speedup vs baseline: 5.0399x; 1.0018x over previous
//
#include <hip/hip_runtime.h>
#include <hip/hip_bf16.h>
#include <math.h>
#include <float.h>

#define NUM_CB 8
#define CB_SIZE 256
#define DIM 128
#define BT (16 * 16384)                  // 262144 tokens
#define Q_ELEMS ((size_t)BT * DIM)       // 33554432
#define I_ELEMS ((size_t)BT * NUM_CB)    // 2097152

// Pass-A ambiguity margin (validated rounds 6-20). Do not shrink.
#define MARGIN_A 1.5e-4f

typedef short  bf16x8 __attribute__((ext_vector_type(8)));
typedef float  f32x4  __attribute__((ext_vector_type(4)));

__device__ __forceinline__ unsigned short bf16_rne(float f) {
    unsigned int u = __float_as_uint(f);
    u = u + 0x7FFFu + ((u >> 16) & 1u);
    return (unsigned short)(u >> 16);
}
__device__ __forceinline__ float bf16_tof(unsigned short h) {
    return __uint_as_float(((unsigned int)h) << 16);
}
__device__ __forceinline__ unsigned short f2bf(float f) {
    __hip_bfloat16 h = __float2bfloat16(f);
    return *reinterpret_cast<unsigned short*>(&h);
}

// ---------------------------------------------------------------------------
// VALIDATED np emulation (rounds 6-20): pairwise-8 sum-of-squares, no FMA.
// ---------------------------------------------------------------------------
__device__ __forceinline__ float np_sum_sq_128(const float* a) {
#pragma clang fp contract(off)
    float r0 = 0.f, r1 = 0.f, r2 = 0.f, r3 = 0.f,
          r4 = 0.f, r5 = 0.f, r6 = 0.f, r7 = 0.f;
#pragma unroll
    for (int i = 0; i < DIM; i += 8) {
        r0 = r0 + a[i + 0] * a[i + 0];
        r1 = r1 + a[i + 1] * a[i + 1];
        r2 = r2 + a[i + 2] * a[i + 2];
        r3 = r3 + a[i + 3] * a[i + 3];
        r4 = r4 + a[i + 4] * a[i + 4];
        r5 = r5 + a[i + 5] * a[i + 5];
        r6 = r6 + a[i + 6] * a[i + 6];
        r7 = r7 + a[i + 7] * a[i + 7];
    }
    return ((r0 + r1) + (r2 + r3)) + ((r4 + r5) + (r6 + r7));
}

__global__ void rvq_esq_kernel(const float* __restrict__ cb,
                               float* __restrict__ esq) {
    int i = blockIdx.x * blockDim.x + threadIdx.x;   // 0 .. 2047
    if (i >= NUM_CB * CB_SIZE) return;
    esq[i] = np_sum_sq_128(cb + (size_t)i * DIM);
}

// Transposed f32 codebook for coalesced Pass-B reads: cbT[k][d][c]
__global__ void rvq_transpose_kernel(const float* __restrict__ cb,
                                     float* __restrict__ cbT) {
    int idx = blockIdx.x * blockDim.x + threadIdx.x;   // 0 .. 262143
    if (idx >= NUM_CB * DIM * CB_SIZE) return;
    int c = idx & (CB_SIZE - 1);
    int d = (idx >> 8) & (DIM - 1);
    int k = idx >> 15;
    cbT[idx] = cb[((size_t)(k * CB_SIZE + c)) * DIM + d];
}

// ---------------------------------------------------------------------------
// Precompute bf16 hi|lo fragment image in WAVE-COALESCED GLOBAL layout:
// g2[(((k*16 + ctg)*2 + plane)*4 + s)*64 + lane] = plane(hi/lo) bf16x8 of
//   candidate c = ctg*16 + (lane&15), dims 8*(4*s + (lane>>4)) .. +8.
// Each fragment fetch in the main loop is one contiguous 1KB
// global_load_dwordx4 across the wave, L2-resident (1 MB total).
// ---------------------------------------------------------------------------
__global__ void rvq_split2_kernel(const float* __restrict__ cb,
                                  bf16x8* __restrict__ g2) {
    int idx = blockIdx.x * blockDim.x + threadIdx.x;   // 0 .. 65535
    if (idx >= NUM_CB * 16 * 2 * 4 * 64) return;
    int lane  = idx & 63;
    int s     = (idx >> 6) & 3;
    int plane = (idx >> 8) & 1;
    int ctg   = (idx >> 9) & 15;
    int k     = idx >> 13;
    int cand  = ctg * 16 + (lane & 15);
    int slot  = 4 * s + (lane >> 4);
    const float* src = cb + ((size_t)(k * CB_SIZE + cand)) * DIM + slot * 8;
    float4 a = *reinterpret_cast<const float4*>(src);
    float4 b = *reinterpret_cast<const float4*>(src + 4);
    float e[8] = {a.x, a.y, a.z, a.w, b.x, b.y, b.z, b.w};
    bf16x8 v;
#pragma unroll
    for (int i = 0; i < 8; ++i) {
        unsigned short h = bf16_rne(e[i]);
        if (plane == 0) {
            v[i] = (short)h;
        } else {
            float rem = e[i] - bf16_tof(h);
            v[i] = (short)bf16_rne(rem);
        }
    }
    g2[idx] = v;
}

// ---------------------------------------------------------------------------
// Main fused kernel: 128 tokens/block (8 waves x 16), residual in VGPRs.
// SWAPPED MFMA (A = codebook frag, B = residual frag), fragments read
// DIRECTLY from the L2-resident g2 image (coalesced 1KB loads) -- NO LDS
// staging, NO barriers in the main loop.
// __launch_bounds__(512, 3): 85-VGPR cap; kernel measured at 84 VGPR (r20)
// -> 3 blocks/CU = 24 waves/CU = 6 waves/SIMD (was 2 blocks / 16 waves).
// ---------------------------------------------------------------------------
__global__ __launch_bounds__(512, 3) void rvq_mfma_kernel(
    const float* __restrict__ z,
    const float* __restrict__ cb,
    const float* __restrict__ cbT,
    const float* __restrict__ esq,
    const bf16x8* __restrict__ g2,
    float* __restrict__ out_q,
    float* __restrict__ out_idx,
    double* __restrict__ loss_acc) {

    __shared__ __align__(16) float s_rbuf[8][DIM];   // per-wave passB residual
    __shared__ double s_wsum[8];

    const int tid  = threadIdx.x;
    const int wid  = tid >> 6;
    const int lane = tid & 63;
    const int lrow = lane & 15;       // token-in-wave (B col / D col)
    const int lq   = lane >> 4;       // k-chunk group / D row group
    const int tokw = blockIdx.x * 128 + wid * 16;
    const int tok  = tokw + lrow;

    // ---- residual chunks: r[s][i] = z[tok][32s + 8lq + i] ----
    float r[4][8];
    {
        const float* zp = z + (size_t)tok * DIM + 8 * lq;
#pragma unroll
        for (int s = 0; s < 4; ++s) {
            float4 a = *reinterpret_cast<const float4*>(zp + 32 * s);
            float4 b = *reinterpret_cast<const float4*>(zp + 32 * s + 4);
            r[s][0] = a.x; r[s][1] = a.y; r[s][2] = a.z; r[s][3] = a.w;
            r[s][4] = b.x; r[s][5] = b.y; r[s][6] = b.z; r[s][7] = b.w;
        }
    }

    // ---- fast bf16 hi/mid split (HW RNE casts) ----
    bf16x8 ah[4], am[4];
#pragma unroll
    for (int s = 0; s < 4; ++s)
#pragma unroll
        for (int i = 0; i < 8; ++i) {
            unsigned short h = f2bf(r[s][i]);
            float rem = r[s][i] - bf16_tof(h);
            ah[s][i] = (short)h;
            am[s][i] = (short)f2bf(rem);
        }

    double lsum = 0.0;

    for (int k = 0; k < NUM_CB; ++k) {
        const float* esqk = esq + k * CB_SIZE;
        const float* cbk  = cb  + (size_t)k * CB_SIZE * DIM;
        const float* cbTk = cbT + (size_t)k * DIM * CB_SIZE + lane;

        float m1 = FLT_MAX, m2 = FLT_MAX;
        int   i1 = 0x7fffffff;

#pragma unroll 4
        for (int ctg = 0; ctg < 16; ++ctg) {   // 16-candidate column tiles
            // fragments: 8 coalesced 1KB loads from the L2-resident image
            const bf16x8* gp = g2 + ((size_t)(k * 16 + ctg) * 8 * 64) + lane;
            bf16x8 bh[4], bl[4];
#pragma unroll
            for (int s = 0; s < 4; ++s) {
                bh[s] = gp[s * 64];
                bl[s] = gp[(4 + s) * 64];
            }
            f32x4 acc0 = {0.f, 0.f, 0.f, 0.f};
            f32x4 acc1 = {0.f, 0.f, 0.f, 0.f};
            // SWAPPED: A = codebook frag, B = residual frag
            acc0 = __builtin_amdgcn_mfma_f32_16x16x32_bf16(bh[0], ah[0], acc0, 0, 0, 0);
            acc0 = __builtin_amdgcn_mfma_f32_16x16x32_bf16(bh[1], ah[1], acc0, 0, 0, 0);
            acc1 = __builtin_amdgcn_mfma_f32_16x16x32_bf16(bh[2], ah[2], acc1, 0, 0, 0);
            acc1 = __builtin_amdgcn_mfma_f32_16x16x32_bf16(bh[3], ah[3], acc1, 0, 0, 0);
            acc0 = __builtin_amdgcn_mfma_f32_16x16x32_bf16(bh[0], am[0], acc0, 0, 0, 0);
            acc0 = __builtin_amdgcn_mfma_f32_16x16x32_bf16(bh[1], am[1], acc0, 0, 0, 0);
            acc1 = __builtin_amdgcn_mfma_f32_16x16x32_bf16(bh[2], am[2], acc1, 0, 0, 0);
            acc1 = __builtin_amdgcn_mfma_f32_16x16x32_bf16(bh[3], am[3], acc1, 0, 0, 0);
            acc0 = __builtin_amdgcn_mfma_f32_16x16x32_bf16(bl[0], ah[0], acc0, 0, 0, 0);
            acc0 = __builtin_amdgcn_mfma_f32_16x16x32_bf16(bl[1], ah[1], acc0, 0, 0, 0);
            acc1 = __builtin_amdgcn_mfma_f32_16x16x32_bf16(bl[2], ah[2], acc1, 0, 0, 0);
            acc1 = __builtin_amdgcn_mfma_f32_16x16x32_bf16(bl[3], ah[3], acc1, 0, 0, 0);

            // scores: candidate c = ctg*16 + 4*lq + j for THIS lane's token
            float4 ev = *reinterpret_cast<const float4*>(
                esqk + ctg * 16 + 4 * lq);
            const float es[4] = {ev.x, ev.y, ev.z, ev.w};
            const int cb0 = ctg * 16 + 4 * lq;
#pragma unroll
            for (int j = 0; j < 4; ++j) {
                float s = fmaf(-2.0f, acc0[j] + acc1[j], es[j]);
                m2 = fminf(m2, fmaxf(m1, s));
                if (s < m1) { m1 = s; i1 = cb0 + j; }   // ascending c order
            }
        }

        // ============== per-codebook epilogue (wave-internal) ==============
        // cross-lq top-2 lexicographic reduce (2 butterfly steps)
#pragma unroll
        for (int d = 16; d < 64; d <<= 1) {
            float om1 = __shfl_xor(m1, d);
            float om2 = __shfl_xor(m2, d);
            int   oi1 = __shfl_xor(i1, d);
            bool ow = (om1 < m1) || (om1 == m1 && oi1 < i1);
            float lo = ow ? m1 : om1;
            m1 = ow ? om1 : m1;
            i1 = ow ? oi1 : i1;
            m2 = fminf(fminf(m2, om2), lo);
        }
        int cmin = i1;

        // Pass B (rare): exact np argmin, coalesced cbT (validated)
        bool amb = !(m2 - m1 > MARGIN_A);
        unsigned long long mask = __ballot(amb && lane < 16);
        while (mask) {
            int srct = __ffsll(mask) - 1;
            mask &= mask - 1;
            if (lrow == srct) {
#pragma unroll
                for (int s = 0; s < 4; ++s) {
                    float4* dst = reinterpret_cast<float4*>(
                        &s_rbuf[wid][32 * s + 8 * lq]);
                    dst[0] = make_float4(r[s][0], r[s][1], r[s][2], r[s][3]);
                    dst[1] = make_float4(r[s][4], r[s][5], r[s][6], r[s][7]);
                }
            }
            asm volatile("s_waitcnt lgkmcnt(0)" ::: "memory");
            float xs = 0.f;
            if (lane == 0) xs = np_sum_sq_128(&s_rbuf[wid][0]);
            xs = __shfl(xs, 0);

            const float* rb = &s_rbuf[wid][0];
            float a0 = 0.f, a1 = 0.f, a2 = 0.f, a3 = 0.f;
#pragma unroll 8
            for (int d = 0; d < DIM; ++d) {
                float rv = rb[d];
                const float* row = cbTk + (size_t)d * CB_SIZE;
                a0 = fmaf(rv, row[0],   a0);
                a1 = fmaf(rv, row[64],  a1);
                a2 = fmaf(rv, row[128], a2);
                a3 = fmaf(rv, row[192], a3);
            }
            float dd0, dd1, dd2, dd3;
            {
#pragma clang fp contract(off)
                float S0 = xs + esqk[lane];
                float S1 = xs + esqk[lane + 64];
                float S2 = xs + esqk[lane + 128];
                float S3 = xs + esqk[lane + 192];
                dd0 = S0 - 2.0f * a0;
                dd1 = S1 - 2.0f * a1;
                dd2 = S2 - 2.0f * a2;
                dd3 = S3 - 2.0f * a3;
            }
            float bd = dd0; int bc = lane;
            if (dd1 < bd) { bd = dd1; bc = lane + 64; }
            if (dd2 < bd) { bd = dd2; bc = lane + 128; }
            if (dd3 < bd) { bd = dd3; bc = lane + 192; }
#pragma unroll
            for (int d = 1; d < 64; d <<= 1) {
                float od = __shfl_xor(bd, d);
                int   oc = __shfl_xor(bc, d);
                if (od < bd || (od == bd && oc < bc)) { bd = od; bc = oc; }
            }
            if (lrow == srct) cmin = bc;   // all lanes have (bd,bc)
        }

        if (lane < 16)    // lane==lrow owner copy
            out_idx[(size_t)(tokw + lane) * NUM_CB + k] = (float)cmin;

        // residual update + loss
        const float* ep = cbk + (size_t)cmin * DIM + 8 * lq;
        float l0 = 0.f, l1 = 0.f, l2 = 0.f, l3 = 0.f;
#pragma unroll
        for (int s = 0; s < 4; ++s) {
            float4 ev0 = *reinterpret_cast<const float4*>(ep + 32 * s);
            float4 ev1 = *reinterpret_cast<const float4*>(ep + 32 * s + 4);
            float d0 = ev0.x - r[s][0], d1 = ev0.y - r[s][1];
            float d2 = ev0.z - r[s][2], d3 = ev0.w - r[s][3];
            float d4 = ev1.x - r[s][4], d5 = ev1.y - r[s][5];
            float d6 = ev1.z - r[s][6], d7 = ev1.w - r[s][7];
            l0 = fmaf(d0, d0, l0); l1 = fmaf(d1, d1, l1);
            l2 = fmaf(d2, d2, l2); l3 = fmaf(d3, d3, l3);
            l0 = fmaf(d4, d4, l0); l1 = fmaf(d5, d5, l1);
            l2 = fmaf(d6, d6, l2); l3 = fmaf(d7, d7, l3);
            r[s][0] -= ev0.x; r[s][1] -= ev0.y; r[s][2] -= ev0.z; r[s][3] -= ev0.w;
            r[s][4] -= ev1.x; r[s][5] -= ev1.y; r[s][6] -= ev1.z; r[s][7] -= ev1.w;
        }
        lsum += (double)((l0 + l1) + (l2 + l3));

        if (k < NUM_CB - 1) {   // fast re-split for next codebook
#pragma unroll
            for (int s = 0; s < 4; ++s)
#pragma unroll
                for (int i = 0; i < 8; ++i) {
                    unsigned short h = f2bf(r[s][i]);
                    float rem = r[s][i] - bf16_tof(h);
                    ah[s][i] = (short)h;
                    am[s][i] = (short)f2bf(rem);
                }
        }
        // ============== end epilogue =======================================
    }

    // ---- quantized = z - r_final ----
    {
        const float* zp = z + (size_t)tok * DIM + 8 * lq;
        float* op = out_q + (size_t)tok * DIM + 8 * lq;
#pragma unroll
        for (int s = 0; s < 4; ++s) {
            float4 a = *reinterpret_cast<const float4*>(zp + 32 * s);
            float4 b = *reinterpret_cast<const float4*>(zp + 32 * s + 4);
            *reinterpret_cast<float4*>(op + 32 * s) =
                make_float4(a.x - r[s][0], a.y - r[s][1],
                            a.z - r[s][2], a.w - r[s][3]);
            *reinterpret_cast<float4*>(op + 32 * s + 4) =
                make_float4(b.x - r[s][4], b.y - r[s][5],
                            b.z - r[s][6], b.w - r[s][7]);
        }
    }

    // ---- loss reduction ----
    for (int off = 32; off > 0; off >>= 1)
        lsum += __shfl_down(lsum, off, 64);
    if (lane == 0) s_wsum[wid] = lsum;
    __syncthreads();
    if (tid == 0) {
        double t = 0.0;
#pragma unroll
        for (int w = 0; w < 8; ++w) t += s_wsum[w];
        atomicAdd(loss_acc, t);
    }
}

__global__ void rvq_finalize_kernel(const double* __restrict__ loss_acc,
                                    float* __restrict__ out_loss) {
    out_loss[0] = (float)(1.25 * loss_acc[0] / (double)Q_ELEMS);
}

extern "C" void kernel_launch(void* const* d_in, const int* in_sizes, int n_in,
                              void* d_out, int out_size, void* d_ws, size_t ws_size,
                              hipStream_t stream) {
    const float* z  = (const float*)d_in[0];
    const float* cb = (const float*)d_in[1];

    float* out_q    = (float*)d_out;
    float* out_idx  = out_q + Q_ELEMS;
    float* out_loss = out_idx + I_ELEMS;

    double* loss_acc = (double*)d_ws;
    float*  esq      = (float*)((char*)d_ws + 256);              // 8 KB
    bf16x8* g2       = (bf16x8*)((char*)d_ws + 65536);           // 1 MB
    float*  cbT      = (float*)((char*)d_ws + 65536 + 1048576);  // 1 MB

    hipMemsetAsync(loss_acc, 0, sizeof(double), stream);
    rvq_esq_kernel<<<(NUM_CB * CB_SIZE + 255) / 256, 256, 0, stream>>>(cb, esq);
    rvq_split2_kernel<<<(NUM_CB * 16 * 2 * 4 * 64 + 255) / 256, 256, 0,
                        stream>>>(cb, g2);
    rvq_transpose_kernel<<<(NUM_CB * DIM * CB_SIZE + 255) / 256, 256, 0,
                           stream>>>(cb, cbT);
    rvq_mfma_kernel<<<BT / 128, 512, 0, stream>>>(z, cb, cbT, esq, g2,
                                                  out_q, out_idx, loss_acc);
    rvq_finalize_kernel<<<1, 1, 0, stream>>>(loss_acc, out_loss);
}

// Round 22
// 839.994 us; speedup vs baseline: 5.4010x; 1.0716x over previous
//
#include <hip/hip_runtime.h>
#include <hip/hip_bf16.h>
#include <math.h>
#include <float.h>

#define NUM_CB 8
#define CB_SIZE 256
#define DIM 128
#define BT (16 * 16384)                  // 262144 tokens
#define Q_ELEMS ((size_t)BT * DIM)       // 33554432
#define I_ELEMS ((size_t)BT * NUM_CB)    // 2097152

// Pass-A ambiguity margin (validated rounds 6-21). Do not shrink.
#define MARGIN_A 1.5e-4f

typedef short  bf16x8 __attribute__((ext_vector_type(8)));
typedef float  f32x4  __attribute__((ext_vector_type(4)));

__device__ __forceinline__ unsigned short bf16_rne(float f) {
    unsigned int u = __float_as_uint(f);
    u = u + 0x7FFFu + ((u >> 16) & 1u);
    return (unsigned short)(u >> 16);
}
__device__ __forceinline__ float bf16_tof(unsigned short h) {
    return __uint_as_float(((unsigned int)h) << 16);
}
__device__ __forceinline__ unsigned short f2bf(float f) {
    __hip_bfloat16 h = __float2bfloat16(f);
    return *reinterpret_cast<unsigned short*>(&h);
}

// ---------------------------------------------------------------------------
// VALIDATED np emulation (rounds 6-21): pairwise-8 sum-of-squares, no FMA.
// ---------------------------------------------------------------------------
__device__ __forceinline__ float np_sum_sq_128(const float* a) {
#pragma clang fp contract(off)
    float r0 = 0.f, r1 = 0.f, r2 = 0.f, r3 = 0.f,
          r4 = 0.f, r5 = 0.f, r6 = 0.f, r7 = 0.f;
#pragma unroll
    for (int i = 0; i < DIM; i += 8) {
        r0 = r0 + a[i + 0] * a[i + 0];
        r1 = r1 + a[i + 1] * a[i + 1];
        r2 = r2 + a[i + 2] * a[i + 2];
        r3 = r3 + a[i + 3] * a[i + 3];
        r4 = r4 + a[i + 4] * a[i + 4];
        r5 = r5 + a[i + 5] * a[i + 5];
        r6 = r6 + a[i + 6] * a[i + 6];
        r7 = r7 + a[i + 7] * a[i + 7];
    }
    return ((r0 + r1) + (r2 + r3)) + ((r4 + r5) + (r6 + r7));
}

__global__ void rvq_esq_kernel(const float* __restrict__ cb,
                               float* __restrict__ esq) {
    int i = blockIdx.x * blockDim.x + threadIdx.x;   // 0 .. 2047
    if (i >= NUM_CB * CB_SIZE) return;
    esq[i] = np_sum_sq_128(cb + (size_t)i * DIM);
}

// Transposed f32 codebook for coalesced Pass-B reads: cbT[k][d][c]
__global__ void rvq_transpose_kernel(const float* __restrict__ cb,
                                     float* __restrict__ cbT) {
    int idx = blockIdx.x * blockDim.x + threadIdx.x;   // 0 .. 262143
    if (idx >= NUM_CB * DIM * CB_SIZE) return;
    int c = idx & (CB_SIZE - 1);
    int d = (idx >> 8) & (DIM - 1);
    int k = idx >> 15;
    cbT[idx] = cb[((size_t)(k * CB_SIZE + c)) * DIM + d];
}

// ---------------------------------------------------------------------------
// Precompute bf16 hi|lo fragment image in WAVE-COALESCED GLOBAL layout:
// g2[(((k*16 + ctg)*2 + plane)*4 + s)*64 + lane] = plane(hi/lo) bf16x8 of
//   candidate c = ctg*16 + (lane&15), dims 8*(4*s + (lane>>4)) .. +8.
// Each fragment fetch in the main loop is one contiguous 1KB
// global_load_dwordx4 across the wave, L2-resident (1 MB total).
// ---------------------------------------------------------------------------
__global__ void rvq_split2_kernel(const float* __restrict__ cb,
                                  bf16x8* __restrict__ g2) {
    int idx = blockIdx.x * blockDim.x + threadIdx.x;   // 0 .. 65535
    if (idx >= NUM_CB * 16 * 2 * 4 * 64) return;
    int lane  = idx & 63;
    int s     = (idx >> 6) & 3;
    int plane = (idx >> 8) & 1;
    int ctg   = (idx >> 9) & 15;
    int k     = idx >> 13;
    int cand  = ctg * 16 + (lane & 15);
    int slot  = 4 * s + (lane >> 4);
    const float* src = cb + ((size_t)(k * CB_SIZE + cand)) * DIM + slot * 8;
    float4 a = *reinterpret_cast<const float4*>(src);
    float4 b = *reinterpret_cast<const float4*>(src + 4);
    float e[8] = {a.x, a.y, a.z, a.w, b.x, b.y, b.z, b.w};
    bf16x8 v;
#pragma unroll
    for (int i = 0; i < 8; ++i) {
        unsigned short h = bf16_rne(e[i]);
        if (plane == 0) {
            v[i] = (short)h;
        } else {
            float rem = e[i] - bf16_tof(h);
            v[i] = (short)bf16_rne(rem);
        }
    }
    g2[idx] = v;
}

// ---------------------------------------------------------------------------
// Main fused kernel: 128 tokens/block (8 waves x 16), residual in VGPRs.
// SWAPPED MFMA (A = codebook frag, B = residual frag), fragments read
// DIRECTLY from the L2-resident g2 image -- no LDS staging, no barriers.
// This round: FOUR 3-deep MFMA chains (was two 6-deep) + fully unrolled
// 16-ct loop so the scheduler can hoist loads across ct boundaries.
// __launch_bounds__(512, 2): 128-VGPR allocator budget (no spill).
// ---------------------------------------------------------------------------
__global__ __launch_bounds__(512, 2) void rvq_mfma_kernel(
    const float* __restrict__ z,
    const float* __restrict__ cb,
    const float* __restrict__ cbT,
    const float* __restrict__ esq,
    const bf16x8* __restrict__ g2,
    float* __restrict__ out_q,
    float* __restrict__ out_idx,
    double* __restrict__ loss_acc) {

    __shared__ __align__(16) float s_rbuf[8][DIM];   // per-wave passB residual
    __shared__ double s_wsum[8];

    const int tid  = threadIdx.x;
    const int wid  = tid >> 6;
    const int lane = tid & 63;
    const int lrow = lane & 15;       // token-in-wave (B col / D col)
    const int lq   = lane >> 4;       // k-chunk group / D row group
    const int tokw = blockIdx.x * 128 + wid * 16;
    const int tok  = tokw + lrow;

    // ---- residual chunks: r[s][i] = z[tok][32s + 8lq + i] ----
    float r[4][8];
    {
        const float* zp = z + (size_t)tok * DIM + 8 * lq;
#pragma unroll
        for (int s = 0; s < 4; ++s) {
            float4 a = *reinterpret_cast<const float4*>(zp + 32 * s);
            float4 b = *reinterpret_cast<const float4*>(zp + 32 * s + 4);
            r[s][0] = a.x; r[s][1] = a.y; r[s][2] = a.z; r[s][3] = a.w;
            r[s][4] = b.x; r[s][5] = b.y; r[s][6] = b.z; r[s][7] = b.w;
        }
    }

    // ---- fast bf16 hi/mid split (HW RNE casts) ----
    bf16x8 ah[4], am[4];
#pragma unroll
    for (int s = 0; s < 4; ++s)
#pragma unroll
        for (int i = 0; i < 8; ++i) {
            unsigned short h = f2bf(r[s][i]);
            float rem = r[s][i] - bf16_tof(h);
            ah[s][i] = (short)h;
            am[s][i] = (short)f2bf(rem);
        }

    double lsum = 0.0;

    for (int k = 0; k < NUM_CB; ++k) {
        const float* esqk = esq + k * CB_SIZE;
        const float* cbk  = cb  + (size_t)k * CB_SIZE * DIM;
        const float* cbTk = cbT + (size_t)k * DIM * CB_SIZE + lane;

        float m1 = FLT_MAX, m2 = FLT_MAX;
        int   i1 = 0x7fffffff;

#pragma unroll
        for (int ctg = 0; ctg < 16; ++ctg) {   // 16-candidate column tiles
            // fragments: 8 coalesced 1KB loads from the L2-resident image
            const bf16x8* gp = g2 + ((size_t)(k * 16 + ctg) * 8 * 64) + lane;
            bf16x8 bh[4], bl[4];
#pragma unroll
            for (int s = 0; s < 4; ++s) {
                bh[s] = gp[s * 64];
                bl[s] = gp[(4 + s) * 64];
            }
            // FOUR independent 3-deep chains (per-s), halved dep depth.
            f32x4 a0 = {0.f, 0.f, 0.f, 0.f};
            f32x4 a1 = a0, a2 = a0, a3 = a0;
            a0 = __builtin_amdgcn_mfma_f32_16x16x32_bf16(bh[0], ah[0], a0, 0, 0, 0);
            a1 = __builtin_amdgcn_mfma_f32_16x16x32_bf16(bh[1], ah[1], a1, 0, 0, 0);
            a2 = __builtin_amdgcn_mfma_f32_16x16x32_bf16(bh[2], ah[2], a2, 0, 0, 0);
            a3 = __builtin_amdgcn_mfma_f32_16x16x32_bf16(bh[3], ah[3], a3, 0, 0, 0);
            a0 = __builtin_amdgcn_mfma_f32_16x16x32_bf16(bh[0], am[0], a0, 0, 0, 0);
            a1 = __builtin_amdgcn_mfma_f32_16x16x32_bf16(bh[1], am[1], a1, 0, 0, 0);
            a2 = __builtin_amdgcn_mfma_f32_16x16x32_bf16(bh[2], am[2], a2, 0, 0, 0);
            a3 = __builtin_amdgcn_mfma_f32_16x16x32_bf16(bh[3], am[3], a3, 0, 0, 0);
            a0 = __builtin_amdgcn_mfma_f32_16x16x32_bf16(bl[0], ah[0], a0, 0, 0, 0);
            a1 = __builtin_amdgcn_mfma_f32_16x16x32_bf16(bl[1], ah[1], a1, 0, 0, 0);
            a2 = __builtin_amdgcn_mfma_f32_16x16x32_bf16(bl[2], ah[2], a2, 0, 0, 0);
            a3 = __builtin_amdgcn_mfma_f32_16x16x32_bf16(bl[3], ah[3], a3, 0, 0, 0);

            // scores: candidate c = ctg*16 + 4*lq + j for THIS lane's token
            float4 ev = *reinterpret_cast<const float4*>(
                esqk + ctg * 16 + 4 * lq);
            const float es[4] = {ev.x, ev.y, ev.z, ev.w};
            const int cb0 = ctg * 16 + 4 * lq;
#pragma unroll
            for (int j = 0; j < 4; ++j) {
                float cr = (a0[j] + a1[j]) + (a2[j] + a3[j]);
                float s = fmaf(-2.0f, cr, es[j]);
                m2 = fminf(m2, fmaxf(m1, s));
                if (s < m1) { m1 = s; i1 = cb0 + j; }   // ascending c order
            }
        }

        // ============== per-codebook epilogue (wave-internal) ==============
        // cross-lq top-2 lexicographic reduce (2 butterfly steps)
#pragma unroll
        for (int d = 16; d < 64; d <<= 1) {
            float om1 = __shfl_xor(m1, d);
            float om2 = __shfl_xor(m2, d);
            int   oi1 = __shfl_xor(i1, d);
            bool ow = (om1 < m1) || (om1 == m1 && oi1 < i1);
            float lo = ow ? m1 : om1;
            m1 = ow ? om1 : m1;
            i1 = ow ? oi1 : i1;
            m2 = fminf(fminf(m2, om2), lo);
        }
        int cmin = i1;

        // Pass B (rare): exact np argmin, coalesced cbT (validated)
        bool amb = !(m2 - m1 > MARGIN_A);
        unsigned long long mask = __ballot(amb && lane < 16);
        while (mask) {
            int srct = __ffsll(mask) - 1;
            mask &= mask - 1;
            if (lrow == srct) {
#pragma unroll
                for (int s = 0; s < 4; ++s) {
                    float4* dst = reinterpret_cast<float4*>(
                        &s_rbuf[wid][32 * s + 8 * lq]);
                    dst[0] = make_float4(r[s][0], r[s][1], r[s][2], r[s][3]);
                    dst[1] = make_float4(r[s][4], r[s][5], r[s][6], r[s][7]);
                }
            }
            asm volatile("s_waitcnt lgkmcnt(0)" ::: "memory");
            float xs = 0.f;
            if (lane == 0) xs = np_sum_sq_128(&s_rbuf[wid][0]);
            xs = __shfl(xs, 0);

            const float* rb = &s_rbuf[wid][0];
            float a0 = 0.f, a1 = 0.f, a2 = 0.f, a3 = 0.f;
#pragma unroll 8
            for (int d = 0; d < DIM; ++d) {
                float rv = rb[d];
                const float* row = cbTk + (size_t)d * CB_SIZE;
                a0 = fmaf(rv, row[0],   a0);
                a1 = fmaf(rv, row[64],  a1);
                a2 = fmaf(rv, row[128], a2);
                a3 = fmaf(rv, row[192], a3);
            }
            float dd0, dd1, dd2, dd3;
            {
#pragma clang fp contract(off)
                float S0 = xs + esqk[lane];
                float S1 = xs + esqk[lane + 64];
                float S2 = xs + esqk[lane + 128];
                float S3 = xs + esqk[lane + 192];
                dd0 = S0 - 2.0f * a0;
                dd1 = S1 - 2.0f * a1;
                dd2 = S2 - 2.0f * a2;
                dd3 = S3 - 2.0f * a3;
            }
            float bd = dd0; int bc = lane;
            if (dd1 < bd) { bd = dd1; bc = lane + 64; }
            if (dd2 < bd) { bd = dd2; bc = lane + 128; }
            if (dd3 < bd) { bd = dd3; bc = lane + 192; }
#pragma unroll
            for (int d = 1; d < 64; d <<= 1) {
                float od = __shfl_xor(bd, d);
                int   oc = __shfl_xor(bc, d);
                if (od < bd || (od == bd && oc < bc)) { bd = od; bc = oc; }
            }
            if (lrow == srct) cmin = bc;   // all lanes have (bd,bc)
        }

        if (lane < 16)    // lane==lrow owner copy
            out_idx[(size_t)(tokw + lane) * NUM_CB + k] = (float)cmin;

        // residual update + loss
        const float* ep = cbk + (size_t)cmin * DIM + 8 * lq;
        float l0 = 0.f, l1 = 0.f, l2 = 0.f, l3 = 0.f;
#pragma unroll
        for (int s = 0; s < 4; ++s) {
            float4 ev0 = *reinterpret_cast<const float4*>(ep + 32 * s);
            float4 ev1 = *reinterpret_cast<const float4*>(ep + 32 * s + 4);
            float d0 = ev0.x - r[s][0], d1 = ev0.y - r[s][1];
            float d2 = ev0.z - r[s][2], d3 = ev0.w - r[s][3];
            float d4 = ev1.x - r[s][4], d5 = ev1.y - r[s][5];
            float d6 = ev1.z - r[s][6], d7 = ev1.w - r[s][7];
            l0 = fmaf(d0, d0, l0); l1 = fmaf(d1, d1, l1);
            l2 = fmaf(d2, d2, l2); l3 = fmaf(d3, d3, l3);
            l0 = fmaf(d4, d4, l0); l1 = fmaf(d5, d5, l1);
            l2 = fmaf(d6, d6, l2); l3 = fmaf(d7, d7, l3);
            r[s][0] -= ev0.x; r[s][1] -= ev0.y; r[s][2] -= ev0.z; r[s][3] -= ev0.w;
            r[s][4] -= ev1.x; r[s][5] -= ev1.y; r[s][6] -= ev1.z; r[s][7] -= ev1.w;
        }
        lsum += (double)((l0 + l1) + (l2 + l3));

        if (k < NUM_CB - 1) {   // fast re-split for next codebook
#pragma unroll
            for (int s = 0; s < 4; ++s)
#pragma unroll
                for (int i = 0; i < 8; ++i) {
                    unsigned short h = f2bf(r[s][i]);
                    float rem = r[s][i] - bf16_tof(h);
                    ah[s][i] = (short)h;
                    am[s][i] = (short)f2bf(rem);
                }
        }
        // ============== end epilogue =======================================
    }

    // ---- quantized = z - r_final ----
    {
        const float* zp = z + (size_t)tok * DIM + 8 * lq;
        float* op = out_q + (size_t)tok * DIM + 8 * lq;
#pragma unroll
        for (int s = 0; s < 4; ++s) {
            float4 a = *reinterpret_cast<const float4*>(zp + 32 * s);
            float4 b = *reinterpret_cast<const float4*>(zp + 32 * s + 4);
            *reinterpret_cast<float4*>(op + 32 * s) =
                make_float4(a.x - r[s][0], a.y - r[s][1],
                            a.z - r[s][2], a.w - r[s][3]);
            *reinterpret_cast<float4*>(op + 32 * s + 4) =
                make_float4(b.x - r[s][4], b.y - r[s][5],
                            b.z - r[s][6], b.w - r[s][7]);
        }
    }

    // ---- loss reduction ----
    for (int off = 32; off > 0; off >>= 1)
        lsum += __shfl_down(lsum, off, 64);
    if (lane == 0) s_wsum[wid] = lsum;
    __syncthreads();
    if (tid == 0) {
        double t = 0.0;
#pragma unroll
        for (int w = 0; w < 8; ++w) t += s_wsum[w];
        atomicAdd(loss_acc, t);
    }
}

__global__ void rvq_finalize_kernel(const double* __restrict__ loss_acc,
                                    float* __restrict__ out_loss) {
    out_loss[0] = (float)(1.25 * loss_acc[0] / (double)Q_ELEMS);
}

extern "C" void kernel_launch(void* const* d_in, const int* in_sizes, int n_in,
                              void* d_out, int out_size, void* d_ws, size_t ws_size,
                              hipStream_t stream) {
    const float* z  = (const float*)d_in[0];
    const float* cb = (const float*)d_in[1];

    float* out_q    = (float*)d_out;
    float* out_idx  = out_q + Q_ELEMS;
    float* out_loss = out_idx + I_ELEMS;

    double* loss_acc = (double*)d_ws;
    float*  esq      = (float*)((char*)d_ws + 256);              // 8 KB
    bf16x8* g2       = (bf16x8*)((char*)d_ws + 65536);           // 1 MB
    float*  cbT      = (float*)((char*)d_ws + 65536 + 1048576);  // 1 MB

    hipMemsetAsync(loss_acc, 0, sizeof(double), stream);
    rvq_esq_kernel<<<(NUM_CB * CB_SIZE + 255) / 256, 256, 0, stream>>>(cb, esq);
    rvq_split2_kernel<<<(NUM_CB * 16 * 2 * 4 * 64 + 255) / 256, 256, 0,
                        stream>>>(cb, g2);
    rvq_transpose_kernel<<<(NUM_CB * DIM * CB_SIZE + 255) / 256, 256, 0,
                           stream>>>(cb, cbT);
    rvq_mfma_kernel<<<BT / 128, 512, 0, stream>>>(z, cb, cbT, esq, g2,
                                                  out_q, out_idx, loss_acc);
    rvq_finalize_kernel<<<1, 1, 0, stream>>>(loss_acc, out_loss);
}